// Round 10
// baseline (201.748 us; speedup 1.0000x reference)
//
#include <hip/hip_runtime.h>
#include <hip/hip_bf16.h>
#include <hip/hip_fp16.h>

// B=2, N=1024, C=512, H=8, D=64, m=128, p=8
#define Hh 8
#define Bz 2
#define Nn 1024
#define Cc 512
#define Dd 64
#define Mm 128
#define NS_EPS 1e-4f
#define WHITE_EPS 1e-5f
// exp(-s/LAM) = exp2(-s * log2(e)/LAM), LAM=4
#define NEG_L2E_OVER_LAM (-0.3606737602222409f)

__device__ __forceinline__ float h2f(__half v) { return __half2float(v); }
__device__ __forceinline__ __half f2h(float v) { return __float2half(v); }
__device__ __forceinline__ float lapexp(float s) {
  return __builtin_amdgcn_exp2f(s * NEG_L2E_OVER_LAM);
}

typedef _Float16 half8 __attribute__((ext_vector_type(8)));
typedef _Float16 half4v __attribute__((ext_vector_type(4)));
typedef _Float16 half2v __attribute__((ext_vector_type(2)));
typedef unsigned int uint4v __attribute__((ext_vector_type(4)));
typedef float float4v __attribute__((ext_vector_type(4)));

// packed-f16 L1 accumulate: s += sum_i |a_i - b_i|  (8 f16 elems)
// 4 v_pk_add(neg) + 4 v_and + 4 v_dot2_f32_f16  = 12 VALU / 8 elems
__device__ __forceinline__ float l1dot(half8 a, half8 b, float s) {
  half8 d = a - b;
  uint4v u = __builtin_bit_cast(uint4v, d);
  u &= 0x7FFF7FFFu;
  const half2v one = {(_Float16)1.f, (_Float16)1.f};
#pragma unroll
  for (int p = 0; p < 4; ++p) {
    half2v dv = __builtin_bit_cast(half2v, (unsigned int)u[p]);
    s = __builtin_amdgcn_fdot2(dv, one, s, false);
  }
  return s;
}

// ---------------------------------------------------------------------------
// K1: QKV GEMM via MFMA f16. M=2048, N=1536, K=512. Block tile 128x128.
__global__ __launch_bounds__(256) void qkv_gemm(
    const float* __restrict__ x, const float* __restrict__ w,
    const float* __restrict__ bias, const float* __restrict__ tm,
    __half* __restrict__ Q, __half* __restrict__ K, __half* __restrict__ V) {
  __shared__ _Float16 As[128 * 40];
  __shared__ _Float16 Bs[128 * 40];
  int m0 = blockIdx.x * 128, n0 = blockIdx.y * 128;
  int tid = threadIdx.x;
  int lane = tid & 63, wv = tid >> 6;
  int wm = (wv >> 1) * 64, wn = (wv & 1) * 64;
  int l15 = lane & 15, quad = lane >> 4;
  int srow = tid >> 1, shalf = tid & 1;
  float4v acc[4][4] = {};
  for (int k0 = 0; k0 < 512; k0 += 32) {
    __syncthreads();
    {
      const float4* ga = (const float4*)(x + (size_t)(m0 + srow) * 512 + k0 + shalf * 16);
      const float4* gb = (const float4*)(w + (size_t)(n0 + srow) * 512 + k0 + shalf * 16);
      float4 a0 = ga[0], a1 = ga[1], a2 = ga[2], a3 = ga[3];
      float4 b0 = gb[0], b1 = gb[1], b2 = gb[2], b3 = gb[3];
      half8 ha0 = {(_Float16)a0.x, (_Float16)a0.y, (_Float16)a0.z, (_Float16)a0.w,
                   (_Float16)a1.x, (_Float16)a1.y, (_Float16)a1.z, (_Float16)a1.w};
      half8 ha1 = {(_Float16)a2.x, (_Float16)a2.y, (_Float16)a2.z, (_Float16)a2.w,
                   (_Float16)a3.x, (_Float16)a3.y, (_Float16)a3.z, (_Float16)a3.w};
      half8 hb0 = {(_Float16)b0.x, (_Float16)b0.y, (_Float16)b0.z, (_Float16)b0.w,
                   (_Float16)b1.x, (_Float16)b1.y, (_Float16)b1.z, (_Float16)b1.w};
      half8 hb1 = {(_Float16)b2.x, (_Float16)b2.y, (_Float16)b2.z, (_Float16)b2.w,
                   (_Float16)b3.x, (_Float16)b3.y, (_Float16)b3.z, (_Float16)b3.w};
      int lo = srow * 40 + shalf * 16;
      *(half8*)&As[lo] = ha0;
      *(half8*)&As[lo + 8] = ha1;
      *(half8*)&Bs[lo] = hb0;
      *(half8*)&Bs[lo + 8] = hb1;
    }
    __syncthreads();
    half8 a[4], b[4];
#pragma unroll
    for (int mt = 0; mt < 4; ++mt)
      a[mt] = *(const half8*)&As[(wm + mt * 16 + l15) * 40 + quad * 8];
#pragma unroll
    for (int nt = 0; nt < 4; ++nt)
      b[nt] = *(const half8*)&Bs[(wn + nt * 16 + l15) * 40 + quad * 8];
#pragma unroll
    for (int mt = 0; mt < 4; ++mt)
#pragma unroll
      for (int nt = 0; nt < 4; ++nt)
        acc[mt][nt] =
            __builtin_amdgcn_mfma_f32_16x16x32_f16(a[mt], b[nt], acc[mt][nt], 0, 0, 0);
  }
#pragma unroll
  for (int mt = 0; mt < 4; ++mt) {
#pragma unroll
    for (int r = 0; r < 4; ++r) {
      int row = m0 + wm + mt * 16 + quad * 4 + r;
      int b_ = row >> 10, n_ = row & 1023;
      float t = tm[b_ * 1024 + n_];
#pragma unroll
      for (int nt = 0; nt < 4; ++nt) {
        int c3 = n0 + wn + nt * 16 + l15;
        float v = (acc[mt][nt][r] + bias[c3]) * t;
        int sec = c3 >> 9, ch = c3 & 511;
        __half* dst = (sec == 0) ? Q : (sec == 1 ? K : V);
        dst[(size_t)b_ * (Nn * Cc) + (size_t)n_ * 512 + ch] = f2h(v);
      }
    }
  }
}

// ---------------------------------------------------------------------------
// M1 v6: phase-1, f16 LDS tiles + packed-f16 L1 via v_dot2_f32_f16.
// Block order: wbuild (0..127, longest per-block) || stats (128..639) ||
// ktv (640..1151). Inline pooling (QL/KL rounded to f16, matching the
// original pipeline's __half QL/KL).
__global__ __launch_bounds__(256) void fused_phase1(
    const __half* __restrict__ Q, const __half* __restrict__ K,
    const __half* __restrict__ V, const float* __restrict__ tm,
    __half* __restrict__ Wh, float* __restrict__ KTVp,
    float* __restrict__ PS, __half* __restrict__ Pbuf) {
  __shared__ __align__(16) char smem[25984];
  int id = blockIdx.x;
  int tid = threadIdx.x;
  if (id < 128) {
    // ---------------- wbuild body (f16 kls/qs; fdot2 inner) ----------------
    int it = id >> 4, bh = id & 15;
    int b = bh >> 3, h = bh & 7;
    int i0 = it * 16;
    _Float16* kls16 = (_Float16*)smem;           // 128*72*2 = 18432
    _Float16* qs16 = (_Float16*)(smem + 18432);  // 16*72*2 = 2304
    float* pm2 = (float*)(smem + 20736);         // 1024 (128x2)
    float* tms = (float*)(smem + 21760);         // 4096 (1024)
    _Float16* ps16 = (_Float16*)(smem + 21760);  // 4224 (16x132) overlaps tms
    for (int e = tid; e < 1024; e += 256) tms[e] = tm[b * 1024 + e];
    __syncthreads();
    if (tid < 128) {
      float pm = 0.f;
#pragma unroll
      for (int i = 0; i < 8; ++i) pm += tms[tid * 8 + i];
      pm *= 0.125f;
      pm2[tid * 2] = 0.125f / fmaxf(pm, 1e-6f);
      pm2[tid * 2 + 1] = (pm > 0.f) ? 1.f : 0.f;
    }
    __syncthreads();
    {
      const __half* Kb = K + (size_t)b * (Nn * Cc) + (size_t)(h * 64) * 1024;
      const __half* Qb = Q + (size_t)b * (Nn * Cc) + (size_t)(h * 64) * 1024;
      // KL all 128 rows: thread (j=g>>3, cq=g&7) pools 8 ch -> half8 write.
#pragma unroll
      for (int k = 0; k < 4; ++k) {
        int g = k * 256 + tid;
        int j = g >> 3, cq = g & 7;
        float pv = pm2[j * 2];
        _Float16 r[8];
#pragma unroll
        for (int i = 0; i < 8; ++i) {
          int c = cq * 8 + i;
          half8 v = *(const half8*)(Kb + (size_t)c * 1024 + j * 8);
          float s = 0.f;
#pragma unroll
          for (int xx = 0; xx < 8; ++xx) s += (float)v[xx] * tms[j * 8 + xx];
          r[i] = (_Float16)(s * pv);
        }
        half8 w0 = {r[0], r[1], r[2], r[3], r[4], r[5], r[6], r[7]};
        *(half8*)&kls16[j * 72 + cq * 8] = w0;
      }
      // QL rows i0..i0+15: thread (il=tid>>4, cq=tid&15) pools 4 ch -> half4.
      {
        int il = tid >> 4, cq = tid & 15;
        float pv = pm2[(i0 + il) * 2];
        _Float16 r[4];
#pragma unroll
        for (int i = 0; i < 4; ++i) {
          int c = cq * 4 + i;
          half8 v = *(const half8*)(Qb + (size_t)c * 1024 + (i0 + il) * 8);
          float s = 0.f;
#pragma unroll
          for (int xx = 0; xx < 8; ++xx) s += (float)v[xx] * tms[(i0 + il) * 8 + xx];
          r[i] = (_Float16)(s * pv);
        }
        half4v w0 = {r[0], r[1], r[2], r[3]};
        *(half4v*)&qs16[il * 72 + cq * 4] = w0;
      }
    }
    __syncthreads();
    int jg = tid & 63, ng = tid >> 6;
    int j = jg * 2;
    const half8* kAp = (const half8*)&kls16[j * 72];
    const half8* kBp = (const half8*)&kls16[(j + 1) * 72];
    float sA[4] = {}, sB[4] = {};
#pragma unroll
    for (int i = 0; i < 8; ++i) {
      int dq = (i + jg) & 7;
      half8 ka = kAp[dq];
      half8 kb = kBp[dq];
#pragma unroll
      for (int r = 0; r < 4; ++r) {
        half8 qv = *(const half8*)&qs16[(ng * 4 + r) * 72 + dq * 8];
        sA[r] = l1dot(qv, ka, sA[r]);
        sB[r] = l1dot(qv, kb, sB[r]);
      }
    }
    float lmA = pm2[j * 2 + 1], lmB = pm2[(j + 1) * 2 + 1];
#pragma unroll
    for (int r = 0; r < 4; ++r) {
      int i = i0 + ng * 4 + r;
      float lmi = pm2[i * 2 + 1];
      float prA = lmi * lmA, prB = lmi * lmB;
      float dA = (i == j) ? 1.f : 0.f;
      float dB = (i == j + 1) ? 1.f : 0.f;
      ps16[(ng * 4 + r) * 132 + j] =
          (_Float16)(lapexp(sA[r]) * prA + dA * (1.f - prA) + dA * NS_EPS);
      ps16[(ng * 4 + r) * 132 + j + 1] =
          (_Float16)(lapexp(sB[r]) * prB + dB * (1.f - prB) + dB * NS_EPS);
    }
    __syncthreads();
    for (int e = tid; e < 2048; e += 256) {
      _Float16 v = ps16[(e >> 7) * 132 + (e & 127)];
      Wh[(size_t)bh * (Mm * Mm) + (size_t)(i0 + (e >> 7)) * 128 + (e & 127)] =
          *(__half*)&v;
    }
  } else if (id < 640) {
    // ---------------- stats body (f16 kls/Qs; fdot2 inner) -----------------
    int sid = id - 128;
    int jt = sid & 3, bh = (sid >> 2) & 15, nc = sid >> 6;  // nc in [0,8)
    int b = bh >> 3, h = bh & 7;
    int j0 = jt * 32;
    _Float16* kls16 = (_Float16*)smem;           // 32*72*2 = 4608
    _Float16* Qs16 = (_Float16*)(smem + 4608);   // 4608
    float* red = (float*)(smem + 9216);          // 3072
    float* tms = (float*)(smem + 12288);         // 1024 (256 f32)
    float* pmi = (float*)(smem + 13312);         // 128 (32)
    float* lmv = (float*)(smem + 13440);         // 128 (32)
    int u0 = j0 * 8;
    tms[tid] = tm[b * 1024 + u0 + tid];
    __syncthreads();
    if (tid < 32) {
      float pm = 0.f;
#pragma unroll
      for (int i = 0; i < 8; ++i) pm += tms[tid * 8 + i];
      pm *= 0.125f;
      pmi[tid] = 0.125f / fmaxf(pm, 1e-6f);
      lmv[tid] = (pm > 0.f) ? 1.f : 0.f;
    }
    __syncthreads();
    {
      // thread (jl=tid>>3, cq=tid&7) pools 8 channels -> half8 write.
      const __half* Kb = K + (size_t)b * (Nn * Cc) + (size_t)(h * 64) * 1024;
      int jl = tid >> 3, cq = tid & 7;
      float pv = pmi[jl];
      _Float16 r[8];
#pragma unroll
      for (int i = 0; i < 8; ++i) {
        int c = cq * 8 + i;
        half8 v = *(const half8*)(Kb + (size_t)c * 1024 + u0 + jl * 8);
        float s = 0.f;
#pragma unroll
        for (int xx = 0; xx < 8; ++xx) s += (float)v[xx] * tms[jl * 8 + xx];
        r[i] = (_Float16)(s * pv);
      }
      half8 w0 = {r[0], r[1], r[2], r[3], r[4], r[5], r[6], r[7]};
      *(half8*)&kls16[jl * 72 + cq * 8] = w0;
    }
    int sr = tid >> 3, sd8 = (tid & 7) * 8;
    int jq = tid & 15, nq = tid >> 4;
    float lmA = 0.f, lmB = 0.f;
    float aA1 = 0.f, aA2 = 0.f, aA3 = 0.f, aB1 = 0.f, aB2 = 0.f, aB3 = 0.f;
    int jA = j0 + jq * 2, jB = jA + 1;
    for (int nt = 0; nt < 4; ++nt) {
      int n0 = nc * 128 + nt * 32;
      __syncthreads();
      if (nt == 0) { lmA = lmv[jq * 2]; lmB = lmv[jq * 2 + 1]; }
      {
        // raw f16 copy of Q tile (no conversion)
        size_t gi = (size_t)b * (Nn * Cc) + (size_t)(n0 + sr) * 512 + h * 64 + sd8;
        half8 kv = *(const half8*)(Q + gi);
        *(half8*)&Qs16[sr * 72 + sd8] = kv;
      }
      __syncthreads();
      const half8* q0p = (const half8*)&kls16[(jq * 2) * 72];
      const half8* q1p = (const half8*)&kls16[(jq * 2 + 1) * 72];
      const half8* k0p = (const half8*)&Qs16[(nq * 2) * 72];
      const half8* k1p = (const half8*)&Qs16[(nq * 2 + 1) * 72];
      float s00 = 0.f, s01 = 0.f, s10 = 0.f, s11 = 0.f;
#pragma unroll
      for (int i = 0; i < 8; ++i) {
        int dq = (i + tid) & 7;
        half8 q0 = q0p[dq], q1 = q1p[dq];
        half8 k0 = k0p[dq], k1 = k1p[dq];
        s00 = l1dot(q0, k0, s00);
        s01 = l1dot(q0, k1, s01);
        s10 = l1dot(q1, k0, s10);
        s11 = l1dot(q1, k1, s11);
      }
      int nA = n0 + nq * 2, nB = nA + 1;
      float tA = tm[b * 1024 + nA], tB = tm[b * 1024 + nB];
      float xAa = lapexp(s00) * lmA;
      float xAb = lapexp(s01) * lmA;
      float xBa = lapexp(s10) * lmB;
      float xBb = lapexp(s11) * lmB;
      __half2 pA; pA.x = f2h(xAa); pA.y = f2h(xBa);
      __half2 pB; pB.x = f2h(xAb); pB.y = f2h(xBb);
      *(__half2*)&Pbuf[((size_t)bh * 1024 + nA) * 128 + jA] = pA;
      *(__half2*)&Pbuf[((size_t)bh * 1024 + nB) * 128 + jA] = pB;
      float xt;
      xt = xAa * tA; aA1 += xt; aA2 += xt * xt; aA3 += xt * tA;
      xt = xAb * tB; aA1 += xt; aA2 += xt * xt; aA3 += xt * tB;
      xt = xBa * tA; aB1 += xt; aB2 += xt * xt; aB3 += xt * tA;
      xt = xBb * tB; aB1 += xt; aB2 += xt * xt; aB3 += xt * tB;
    }
    int jl = jq * 2;
    red[(jl * 8 + nq) * 3 + 0] = aA1;
    red[(jl * 8 + nq) * 3 + 1] = aA2;
    red[(jl * 8 + nq) * 3 + 2] = aA3;
    red[((jl + 1) * 8 + nq) * 3 + 0] = aB1;
    red[((jl + 1) * 8 + nq) * 3 + 1] = aB2;
    red[((jl + 1) * 8 + nq) * 3 + 2] = aB3;
    __syncthreads();
    if (tid < 32) {
      float s1 = 0.f, s2 = 0.f, s3 = 0.f;
#pragma unroll
      for (int q = 0; q < 8; ++q) {
        s1 += red[(tid * 8 + q) * 3 + 0];
        s2 += red[(tid * 8 + q) * 3 + 1];
        s3 += red[(tid * 8 + q) * 3 + 2];
      }
      size_t base = ((size_t)(nc * 16 + bh) * 128 + j0 + tid) * 3;
      PS[base] = s1; PS[base + 1] = s2; PS[base + 2] = s3;
    }
  } else {
    // ---------------- ktv body (f16 qls/Ks; fdot2 inner; f32 Vs) -----------
    int kid = id - 640;
    int jt = kid & 7, bh = (kid >> 3) & 15, nc = kid >> 7;  // nc in [0,4)
    int b = bh >> 3, h = bh & 7;
    int j0 = jt * 16;
    _Float16* qls16 = (_Float16*)smem;           // 16*72*2 = 2304
    _Float16* Ks16 = (_Float16*)(smem + 2304);   // 32*72*2 = 4608
    float* Vs = (float*)(smem + 6912);           // 32*68*4 = 8704
    float* P = (float*)(smem + 15616);           // 32*20*4 = 2560
    float* tms = (float*)(smem + 18176);         // 512 (128 f32)
    float* pmi = (float*)(smem + 18688);         // 64 (16)
    float* lmv = (float*)(smem + 18752);         // 64 (16)
    int u0 = j0 * 8;
    if (tid < 128) tms[tid] = tm[b * 1024 + u0 + tid];
    __syncthreads();
    if (tid < 16) {
      float pm = 0.f;
#pragma unroll
      for (int i = 0; i < 8; ++i) pm += tms[tid * 8 + i];
      pm *= 0.125f;
      pmi[tid] = 0.125f / fmaxf(pm, 1e-6f);
      lmv[tid] = (pm > 0.f) ? 1.f : 0.f;
    }
    __syncthreads();
    {
      // thread (jl=tid>>4, cq=tid&15) pools 4 channels -> half4 write.
      const __half* Qb = Q + (size_t)b * (Nn * Cc) + (size_t)(h * 64) * 1024;
      int jl_ = tid >> 4, cq = tid & 15;
      float pv = pmi[jl_];
      _Float16 r[4];
#pragma unroll
      for (int i = 0; i < 4; ++i) {
        int c = cq * 4 + i;
        half8 v = *(const half8*)(Qb + (size_t)c * 1024 + u0 + jl_ * 8);
        float s = 0.f;
#pragma unroll
        for (int xx = 0; xx < 8; ++xx) s += (float)v[xx] * tms[jl_ * 8 + xx];
        r[i] = (_Float16)(s * pv);
      }
      half4v w0 = {r[0], r[1], r[2], r[3]};
      *(half4v*)&qls16[jl_ * 72 + cq * 4] = w0;
    }
    int sr = tid >> 3, sd8 = (tid & 7) * 8;
    int jq = tid & 15, nq = tid >> 4;   // P compute: 16 j x 16 n-pairs
    int jl = tid >> 4, dq4 = tid & 15;  // PV: 16 j x 16 d-quads
    float acc[4] = {};
    for (int nt = 0; nt < 8; ++nt) {
      int n0 = nc * 256 + nt * 32;
      __syncthreads();
      {
        size_t gi = (size_t)b * (Nn * Cc) + (size_t)(n0 + sr) * 512 + h * 64 + sd8;
        half8 kv = *(const half8*)(K + gi);
        half8 vv = *(const half8*)(V + gi);
        *(half8*)&Ks16[sr * 72 + sd8] = kv;  // raw f16 copy
        float4 v0 = {(float)vv[0], (float)vv[1], (float)vv[2], (float)vv[3]};
        float4 v1 = {(float)vv[4], (float)vv[5], (float)vv[6], (float)vv[7]};
        *(float4*)&Vs[sr * 68 + sd8] = v0;
        *(float4*)&Vs[sr * 68 + sd8 + 4] = v1;
      }
      __syncthreads();
      {
        const half8* qp = (const half8*)&qls16[jq * 72];
        const half8* k0p = (const half8*)&Ks16[(nq * 2) * 72];
        const half8* k1p = (const half8*)&Ks16[(nq * 2 + 1) * 72];
        float s0 = 0.f, s1 = 0.f;
#pragma unroll
        for (int i = 0; i < 8; ++i) {
          int dq = (i + tid) & 7;
          half8 qv = qp[dq];
          half8 k0 = k0p[dq], k1 = k1p[dq];
          s0 = l1dot(qv, k0, s0);
          s1 = l1dot(qv, k1, s1);
        }
        P[(nq * 2) * 20 + jq] = lapexp(s0);
        P[(nq * 2 + 1) * 20 + jq] = lapexp(s1);
      }
      __syncthreads();
      {
#pragma unroll 8
        for (int n = 0; n < 32; ++n) {
          float p = P[n * 20 + jl];
          float4 v = *(const float4*)&Vs[n * 68 + dq4 * 4];
          acc[0] += p * v.x; acc[1] += p * v.y; acc[2] += p * v.z; acc[3] += p * v.w;
        }
      }
    }
    {
      float lm = lmv[jl];
      float* dst = &KTVp[((size_t)nc * 16 + bh) * 8192 + (size_t)(j0 + jl) * 64 + dq4 * 4];
      float4 o = {acc[0] * lm, acc[1] * lm, acc[2] * lm, acc[3] * lm};
      *(float4*)dst = o;
    }
  }
}

// ---------------------------------------------------------------------------
// M2 v2: 1024-thread blocks. Blocks 0..15: ns_solve (16 waves, 32x32 tiles)
// + fused ctx. Block 16: stats_final.
__global__ __launch_bounds__(1024) void fused_phase2(
    const __half* __restrict__ Wh, const float* __restrict__ KTVp,
    const float* __restrict__ PS, const float* __restrict__ tm,
    __half* __restrict__ CTX, float* __restrict__ MU, float* __restrict__ RS) {
  __shared__ __align__(16) char smem[143360];
  int tid = threadIdx.x;
  if (blockIdx.x < 16) {
    // ---------------- ns_solve + ctx body ----------------
    int bh = blockIdx.x;
    _Float16* Ws = (_Float16*)smem;              // 34816
    _Float16* Xa = (_Float16*)(smem + 34816);    // 34816
    _Float16* Xb = (_Float16*)(smem + 69632);    // 34816
    _Float16* Tt = (_Float16*)(smem + 104448);   // 34816
    float* red = (float*)(smem + 139264);        // 4096
    const __half* Wb = Wh + (size_t)bh * 16384;
    float fro = 0.f;
    for (int e = tid; e < 16384; e += 1024) {
      float wv = h2f(Wb[e]);
      Ws[(e >> 7) * 136 + (e & 127)] = (_Float16)wv;
      fro += wv * wv;
    }
    red[tid] = fro;
    __syncthreads();
    for (int off = 512; off > 0; off >>= 1) {
      if (tid < off) red[tid] += red[tid + off];
      __syncthreads();
    }
    float scale = 2.f / (sqrtf(red[0]) + 1e-8f);
    for (int e = tid; e < 16384; e += 1024) {
      int i = e >> 7, k = e & 127;
      Xa[i * 136 + k] = (_Float16)(scale * (float)Ws[k * 136 + i]);
      Xb[i * 136 + k] = (_Float16)(scale * (float)Ws[i * 136 + k]);
    }
    __syncthreads();
    int lane = tid & 63, wv_ = tid >> 6;            // 16 waves
    int wm = (wv_ >> 2) * 32, wn = (wv_ & 3) * 32;  // 4x4 wave grid
    int l15 = lane & 15, quad = lane >> 4;
    for (int it = 0; it < 5; ++it) {
      {
        float4v acc[2][2] = {};
#pragma unroll
        for (int kt = 0; kt < 4; ++kt) {
          half8 a[2], b[2];
#pragma unroll
          for (int mt = 0; mt < 2; ++mt)
            a[mt] = *(const half8*)&Ws[(wm + mt * 16 + l15) * 136 + kt * 32 + quad * 8];
#pragma unroll
          for (int nt = 0; nt < 2; ++nt)
            b[nt] = *(const half8*)&Xb[(wn + nt * 16 + l15) * 136 + kt * 32 + quad * 8];
#pragma unroll
          for (int mt = 0; mt < 2; ++mt)
#pragma unroll
            for (int nt = 0; nt < 2; ++nt)
              acc[mt][nt] =
                  __builtin_amdgcn_mfma_f32_16x16x32_f16(a[mt], b[nt], acc[mt][nt], 0, 0, 0);
        }
#pragma unroll
        for (int mt = 0; mt < 2; ++mt)
#pragma unroll
          for (int r = 0; r < 4; ++r) {
            int i = wm + mt * 16 + quad * 4 + r;
#pragma unroll
            for (int nt = 0; nt < 2; ++nt) {
              int j = wn + nt * 16 + l15;
              Tt[j * 136 + i] = (_Float16)(((i == j) ? 2.f : 0.f) - acc[mt][nt][r]);
            }
          }
      }
      __syncthreads();
      {
        float4v acc[2][2] = {};
#pragma unroll
        for (int kt = 0; kt < 4; ++kt) {
          half8 a[2], b[2];
#pragma unroll
          for (int mt = 0; mt < 2; ++mt)
            a[mt] = *(const half8*)&Xa[(wm + mt * 16 + l15) * 136 + kt * 32 + quad * 8];
#pragma unroll
          for (int nt = 0; nt < 2; ++nt)
            b[nt] = *(const half8*)&Tt[(wn + nt * 16 + l15) * 136 + kt * 32 + quad * 8];
#pragma unroll
          for (int mt = 0; mt < 2; ++mt)
#pragma unroll
            for (int nt = 0; nt < 2; ++nt)
              acc[mt][nt] =
                  __builtin_amdgcn_mfma_f32_16x16x32_f16(a[mt], b[nt], acc[mt][nt], 0, 0, 0);
        }
        __syncthreads();
#pragma unroll
        for (int mt = 0; mt < 2; ++mt)
#pragma unroll
          for (int r = 0; r < 4; ++r) {
            int i = wm + mt * 16 + quad * 4 + r;
#pragma unroll
            for (int nt = 0; nt < 2; ++nt) {
              int j = wn + nt * 16 + l15;
              _Float16 v = (_Float16)acc[mt][nt][r];
              Xa[i * 136 + j] = v;
              Xb[j * 136 + i] = v;
            }
          }
      }
      __syncthreads();
    }
    // ---- fused ctx: KTV = sum_nc KTVp; CTX = X @ KTV.
    float* KTVs = (float*)smem;  // reuse Ws region
    for (int e = tid; e < 8192; e += 1024) {
      float s = KTVp[(size_t)bh * 8192 + e];
#pragma unroll
      for (int nc = 1; nc < 4; ++nc) s += KTVp[((size_t)nc * 16 + bh) * 8192 + e];
      KTVs[(e >> 6) * 68 + (e & 63)] = s;
    }
    __syncthreads();
    int i = tid >> 3, d0 = (tid & 7) * 8;
    float a0 = 0.f, a1 = 0.f, a2 = 0.f, a3 = 0.f;
    float a4 = 0.f, a5 = 0.f, a6 = 0.f, a7 = 0.f;
#pragma unroll 4
    for (int j = 0; j < 128; ++j) {
      float xv = (float)Xa[i * 136 + j];
      float4 k0 = *(const float4*)&KTVs[j * 68 + d0];
      float4 k1 = *(const float4*)&KTVs[j * 68 + d0 + 4];
      a0 += xv * k0.x; a1 += xv * k0.y; a2 += xv * k0.z; a3 += xv * k0.w;
      a4 += xv * k1.x; a5 += xv * k1.y; a6 += xv * k1.z; a7 += xv * k1.w;
    }
    half8 hout = {(_Float16)a0, (_Float16)a1, (_Float16)a2, (_Float16)a3,
                  (_Float16)a4, (_Float16)a5, (_Float16)a6, (_Float16)a7};
    *(half8*)(CTX + (size_t)bh * 8192 + (size_t)i * 64 + d0) = hout;
  } else {
    // ---------------- stats_final body (1024 threads) ----------------
    float (*red2)[2] = (float(*)[2])smem;       // 8192
    float* ts = (float*)(smem + 8192);          // 8
    float a = 0.f, c = 0.f;
    for (int i = tid; i < 2048; i += 1024) { float t = tm[i]; a += t; c += t * t; }
    red2[tid][0] = a; red2[tid][1] = c;
    __syncthreads();
    for (int off = 512; off > 0; off >>= 1) {
      if (tid < off) { red2[tid][0] += red2[tid + off][0]; red2[tid][1] += red2[tid + off][1]; }
      __syncthreads();
    }
    if (tid == 0) { ts[0] = red2[0][0]; ts[1] = red2[0][1]; }
    __syncthreads();
    int hj = tid;
    int h = hj >> 7, j = hj & 127;
    float s1 = 0.f, s2 = 0.f, s3 = 0.f;
#pragma unroll
    for (int nc = 0; nc < 8; ++nc)
#pragma unroll
      for (int b = 0; b < 2; ++b) {
        const float* p = PS + ((size_t)(nc * 16 + b * 8 + h) * 128 + j) * 3;
        s1 += p[0]; s2 += p[1]; s3 += p[2];
      }
    float valid = fmaxf(ts[0], 1.f);
    float mu = s1 / valid;
    float var = (s2 - 2.f * mu * s3 + mu * mu * ts[1]) / valid;
    var = fmaxf(var, 0.f);
    MU[hj] = mu;
    RS[hj] = rsqrtf(var + WHITE_EPS);
  }
}

// ---------------------------------------------------------------------------
// K12: ga v6 — 32-row n-tiles (grid 512 = 2 blocks/CU); direct conv loads.
__global__ __launch_bounds__(256) void ga_fused(
    const __half* __restrict__ Pbuf, const float* __restrict__ MU,
    const float* __restrict__ RS, const __half* __restrict__ CTXg,
    const __half* __restrict__ V, const float* __restrict__ dwc_w,
    const float* __restrict__ dwc_b, const float* __restrict__ tm,
    __half* __restrict__ VL) {
  int bh = blockIdx.y;
  int b = bh >> 3, h = bh & 7;
  int n0 = blockIdx.x * 32;
  __shared__ __half Ps[32][130];
  __shared__ __align__(16) __half2 ctx2[128][32];
  __shared__ float musr[128][2];
  int tid = threadIdx.x;
  for (int e = tid; e < 4096; e += 256)
    Ps[e >> 7][e & 127] = Pbuf[((size_t)bh * 1024 + n0 + (e >> 7)) * 128 + (e & 127)];
  {
    const __half2* cg = (const __half2*)(CTXg + (size_t)bh * 8192);
    for (int e = tid; e < 4096; e += 256) ctx2[e >> 5][e & 31] = cg[e];
  }
  if (tid < 128) { musr[tid][0] = MU[h * 128 + tid]; musr[tid][1] = RS[h * 128 + tid]; }
  __syncthreads();
  int nn = tid >> 4, dq = tid & 15;
  float acc[2][4] = {};
#pragma unroll 2
  for (int j = 0; j < 128; ++j) {
    float mu = musr[j][0], rs = musr[j][1];
    uint2 cc = *(const uint2*)&ctx2[j][dq * 2];
    __half2 c01 = __builtin_bit_cast(__half2, cc.x);
    __half2 c23 = __builtin_bit_cast(__half2, cc.y);
    float c0 = h2f(c01.x), c1 = h2f(c01.y), c2 = h2f(c23.x), c3 = h2f(c23.y);
#pragma unroll
    for (int rr = 0; rr < 2; ++rr) {
      float pj = (h2f(Ps[nn + rr * 16][j]) - mu) * rs;
      acc[rr][0] += pj * c0; acc[rr][1] += pj * c1;
      acc[rr][2] += pj * c2; acc[rr][3] += pj * c3;
    }
  }
#pragma unroll
  for (int rr = 0; rr < 2; ++rr) {
    int t = n0 + nn + rr * 16;
    float tmv = tm[b * 1024 + t];
    float t2 = tmv * tmv;
    float o[4] = {acc[rr][0] * t2, acc[rr][1] * t2, acc[rr][2] * t2, acc[rr][3] * t2};
#pragma unroll
    for (int q = 0; q < 4; ++q) {
      int c = h * 64 + dq * 4 + q;
      float vacc = dwc_b[c];
#pragma unroll
      for (int k = 0; k < 3; ++k) {
        int u = t - 1 + k;
        if (u >= 0 && u < 1024) {
          int n = 2 * c + (u >> 9), ch = u & 511;
          vacc += dwc_w[c * 3 + k] * h2f(V[(size_t)b * (Nn * Cc) + (size_t)n * 512 + ch]);
        }
      }
      o[q] += vacc * tmv;
    }
    size_t base = (size_t)b * (Nn * Cc) + (size_t)t * 512 + h * 64 + dq * 4;
    VL[base] = f2h(o[0]);
    VL[base + 1] = f2h(o[1]);
    VL[base + 2] = f2h(o[2]);
    VL[base + 3] = f2h(o[3]);
  }
}

// ---------------------------------------------------------------------------
// K13: proj via MFMA f16. M=2048, N=512, K=512. 64x64 tiles -> 256 blocks.
__global__ __launch_bounds__(256) void proj_gemm(
    const __half* __restrict__ Ain, const float* __restrict__ w,
    const float* __restrict__ bias, const float* __restrict__ tm,
    float* __restrict__ out) {
  __shared__ _Float16 As[64 * 40];
  __shared__ _Float16 Bs[64 * 40];
  int m0 = blockIdx.x * 64, n0 = blockIdx.y * 64;
  int tid = threadIdx.x;
  int lane = tid & 63, wv = tid >> 6;
  int wm = (wv >> 1) * 32, wn = (wv & 1) * 32;
  int l15 = lane & 15, quad = lane >> 4;
  int srow = tid >> 2, scol = (tid & 3) * 8;
  float4v acc[2][2] = {};
  for (int k0 = 0; k0 < 512; k0 += 32) {
    __syncthreads();
    {
      half8 ha = *(const half8*)(Ain + (size_t)(m0 + srow) * 512 + k0 + scol);
      const float4* gb = (const float4*)(w + (size_t)(n0 + srow) * 512 + k0 + scol);
      float4 b0 = gb[0], b1 = gb[1];
      half8 hb = {(_Float16)b0.x, (_Float16)b0.y, (_Float16)b0.z, (_Float16)b0.w,
                  (_Float16)b1.x, (_Float16)b1.y, (_Float16)b1.z, (_Float16)b1.w};
      int lo = srow * 40 + scol;
      *(half8*)&As[lo] = ha;
      *(half8*)&Bs[lo] = hb;
    }
    __syncthreads();
    half8 a[2], b[2];
#pragma unroll
    for (int mt = 0; mt < 2; ++mt)
      a[mt] = *(const half8*)&As[(wm + mt * 16 + l15) * 40 + quad * 8];
#pragma unroll
    for (int nt = 0; nt < 2; ++nt)
      b[nt] = *(const half8*)&Bs[(wn + nt * 16 + l15) * 40 + quad * 8];
#pragma unroll
    for (int mt = 0; mt < 2; ++mt)
#pragma unroll
      for (int nt = 0; nt < 2; ++nt)
        acc[mt][nt] =
            __builtin_amdgcn_mfma_f32_16x16x32_f16(a[mt], b[nt], acc[mt][nt], 0, 0, 0);
  }
#pragma unroll
  for (int mt = 0; mt < 2; ++mt) {
#pragma unroll
    for (int r = 0; r < 4; ++r) {
      int row = m0 + wm + mt * 16 + quad * 4 + r;
      int b_ = row >> 10, n_ = row & 1023;
      float t = tm[b_ * 1024 + n_];
#pragma unroll
      for (int nt = 0; nt < 2; ++nt) {
        int co = n0 + wn + nt * 16 + l15;
        out[(size_t)row * 512 + co] = (acc[mt][nt][r] + bias[co]) * t;
      }
    }
  }
}

// ---------------------------------------------------------------------------
// Launches: qkv, M1{wbuild||stats||ktv, inline pooling, fdot2}, M2{ns+ctx ||
// stats_final}, ga, proj  (5).
extern "C" void kernel_launch(void* const* d_in, const int* in_sizes, int n_in,
                              void* d_out, int out_size, void* d_ws, size_t ws_size,
                              hipStream_t stream) {
  const float* x      = (const float*)d_in[0];
  const float* tm     = (const float*)d_in[1];
  const float* qkv_w  = (const float*)d_in[2];
  const float* qkv_b  = (const float*)d_in[3];
  const float* proj_w = (const float*)d_in[4];
  const float* proj_b = (const float*)d_in[5];
  const float* dwc_w  = (const float*)d_in[6];
  const float* dwc_b  = (const float*)d_in[7];
  float* out = (float*)d_out;

  char* wsb = (char*)d_ws;
  __half* Qh  = (__half*)(wsb + 0);
  __half* Kh  = (__half*)(wsb + 2097152);
  __half* Vh  = (__half*)(wsb + 4194304);
  __half* VLh = (__half*)(wsb + 6291456);
  float*  KTVp = (float*)(wsb + 6291456);     // aliases VLh (dead until ga)
  float*  MU  = (float*)(wsb + 8913920);
  float*  RS  = (float*)(wsb + 8918016);
  __half* CTX = (__half*)(wsb + 8922112);
  float*  PS  = (float*)(wsb + 9184256);
  __half* Wh  = (__half*)(wsb + 9380864);

  __half* Pbuf = (__half*)d_out;

  qkv_gemm<<<dim3(16, 12), 256, 0, stream>>>(x, qkv_w, qkv_b, tm, Qh, Kh, Vh);
  fused_phase1<<<1152, 256, 0, stream>>>(Qh, Kh, Vh, tm, Wh, KTVp, PS, Pbuf);
  fused_phase2<<<17, 1024, 0, stream>>>(Wh, KTVp, PS, tm, CTX, MU, RS);
  ga_fused<<<dim3(32, 16), 256, 0, stream>>>(Pbuf, MU, RS, CTX, Vh, dwc_w, dwc_b, tm, VLh);
  proj_gemm<<<dim3(32, 8), 256, 0, stream>>>(VLh, proj_w, proj_b, tm, out);
}

// Round 11
// 196.714 us; speedup vs baseline: 1.0256x; 1.0256x over previous
//
#include <hip/hip_runtime.h>
#include <hip/hip_bf16.h>
#include <hip/hip_fp16.h>

// B=2, N=1024, C=512, H=8, D=64, m=128, p=8
#define Hh 8
#define Bz 2
#define Nn 1024
#define Cc 512
#define Dd 64
#define Mm 128
#define NS_EPS 1e-4f
#define WHITE_EPS 1e-5f
// exp(-s/LAM) = exp2(-s * log2(e)/LAM), LAM=4
#define NEG_L2E_OVER_LAM (-0.3606737602222409f)

__device__ __forceinline__ float h2f(__half v) { return __half2float(v); }
__device__ __forceinline__ __half f2h(float v) { return __float2half(v); }
__device__ __forceinline__ float lapexp(float s) {
  return __builtin_amdgcn_exp2f(s * NEG_L2E_OVER_LAM);
}

typedef _Float16 half8 __attribute__((ext_vector_type(8)));
typedef _Float16 half4v __attribute__((ext_vector_type(4)));
typedef float float4v __attribute__((ext_vector_type(4)));

// ---------------------------------------------------------------------------
// K1: QKV GEMM via MFMA f16. M=2048, N=1536, K=512. Block tile 128x128.
__global__ __launch_bounds__(256) void qkv_gemm(
    const float* __restrict__ x, const float* __restrict__ w,
    const float* __restrict__ bias, const float* __restrict__ tm,
    __half* __restrict__ Q, __half* __restrict__ K, __half* __restrict__ V) {
  __shared__ _Float16 As[128 * 40];
  __shared__ _Float16 Bs[128 * 40];
  int m0 = blockIdx.x * 128, n0 = blockIdx.y * 128;
  int tid = threadIdx.x;
  int lane = tid & 63, wv = tid >> 6;
  int wm = (wv >> 1) * 64, wn = (wv & 1) * 64;
  int l15 = lane & 15, quad = lane >> 4;
  int srow = tid >> 1, shalf = tid & 1;
  float4v acc[4][4] = {};
  for (int k0 = 0; k0 < 512; k0 += 32) {
    __syncthreads();
    {
      const float4* ga = (const float4*)(x + (size_t)(m0 + srow) * 512 + k0 + shalf * 16);
      const float4* gb = (const float4*)(w + (size_t)(n0 + srow) * 512 + k0 + shalf * 16);
      float4 a0 = ga[0], a1 = ga[1], a2 = ga[2], a3 = ga[3];
      float4 b0 = gb[0], b1 = gb[1], b2 = gb[2], b3 = gb[3];
      half8 ha0 = {(_Float16)a0.x, (_Float16)a0.y, (_Float16)a0.z, (_Float16)a0.w,
                   (_Float16)a1.x, (_Float16)a1.y, (_Float16)a1.z, (_Float16)a1.w};
      half8 ha1 = {(_Float16)a2.x, (_Float16)a2.y, (_Float16)a2.z, (_Float16)a2.w,
                   (_Float16)a3.x, (_Float16)a3.y, (_Float16)a3.z, (_Float16)a3.w};
      half8 hb0 = {(_Float16)b0.x, (_Float16)b0.y, (_Float16)b0.z, (_Float16)b0.w,
                   (_Float16)b1.x, (_Float16)b1.y, (_Float16)b1.z, (_Float16)b1.w};
      half8 hb1 = {(_Float16)b2.x, (_Float16)b2.y, (_Float16)b2.z, (_Float16)b2.w,
                   (_Float16)b3.x, (_Float16)b3.y, (_Float16)b3.z, (_Float16)b3.w};
      int lo = srow * 40 + shalf * 16;
      *(half8*)&As[lo] = ha0;
      *(half8*)&As[lo + 8] = ha1;
      *(half8*)&Bs[lo] = hb0;
      *(half8*)&Bs[lo + 8] = hb1;
    }
    __syncthreads();
    half8 a[4], b[4];
#pragma unroll
    for (int mt = 0; mt < 4; ++mt)
      a[mt] = *(const half8*)&As[(wm + mt * 16 + l15) * 40 + quad * 8];
#pragma unroll
    for (int nt = 0; nt < 4; ++nt)
      b[nt] = *(const half8*)&Bs[(wn + nt * 16 + l15) * 40 + quad * 8];
#pragma unroll
    for (int mt = 0; mt < 4; ++mt)
#pragma unroll
      for (int nt = 0; nt < 4; ++nt)
        acc[mt][nt] =
            __builtin_amdgcn_mfma_f32_16x16x32_f16(a[mt], b[nt], acc[mt][nt], 0, 0, 0);
  }
#pragma unroll
  for (int mt = 0; mt < 4; ++mt) {
#pragma unroll
    for (int r = 0; r < 4; ++r) {
      int row = m0 + wm + mt * 16 + quad * 4 + r;
      int b_ = row >> 10, n_ = row & 1023;
      float t = tm[b_ * 1024 + n_];
#pragma unroll
      for (int nt = 0; nt < 4; ++nt) {
        int c3 = n0 + wn + nt * 16 + l15;
        float v = (acc[mt][nt][r] + bias[c3]) * t;
        int sec = c3 >> 9, ch = c3 & 511;
        __half* dst = (sec == 0) ? Q : (sec == 1 ? K : V);
        dst[(size_t)b_ * (Nn * Cc) + (size_t)n_ * 512 + ch] = f2h(v);
      }
    }
  }
}

// ---------------------------------------------------------------------------
// M1 v5: phase-1, inline pooling with CONFLICT-FREE grouped stores (float4/
// half8; 2-way max). stats (0..511) || ktv (512..1023) || wbuild (1024..1151).
__global__ __launch_bounds__(256) void fused_phase1(
    const __half* __restrict__ Q, const __half* __restrict__ K,
    const __half* __restrict__ V, const float* __restrict__ tm,
    __half* __restrict__ Wh, float* __restrict__ KTVp,
    float* __restrict__ PS, __half* __restrict__ Pbuf) {
  __shared__ __align__(16) char smem[31232];
  int id = blockIdx.x;
  int tid = threadIdx.x;
  if (id < 512) {
    // ---------------- stats_partial body (pools KL rows j0..j0+32) --------
    int jt = id & 3, bh = (id >> 2) & 15, nc = id >> 6;  // nc in [0,8)
    int b = bh >> 3, h = bh & 7;
    int j0 = jt * 32;
    float* kls = (float*)smem;             // 8704
    float* Qs  = (float*)(smem + 8704);    // 8704
    float* red = (float*)(smem + 17408);   // 3072
    float* tms = (float*)(smem + 20480);   // 1024 (256 f32)
    float* pmi = (float*)(smem + 21504);   // 128 (32)
    float* lmv = (float*)(smem + 21632);   // 128 (32)
    int u0 = j0 * 8;
    tms[tid] = tm[b * 1024 + u0 + tid];
    __syncthreads();
    if (tid < 32) {
      float pm = 0.f;
#pragma unroll
      for (int i = 0; i < 8; ++i) pm += tms[tid * 8 + i];
      pm *= 0.125f;
      pmi[tid] = 0.125f / fmaxf(pm, 1e-6f);
      lmv[tid] = (pm > 0.f) ? 1.f : 0.f;
    }
    __syncthreads();
    {
      // thread (jl=tid>>3, cq=tid&7) pools 8 channels -> 2 float4 writes.
      const __half* Kb = K + (size_t)b * (Nn * Cc) + (size_t)(h * 64) * 1024;
      int jl = tid >> 3, cq = tid & 7;
      float pv = pmi[jl];
      float r[8];
#pragma unroll
      for (int i = 0; i < 8; ++i) {
        int c = cq * 8 + i;
        half8 v = *(const half8*)(Kb + (size_t)c * 1024 + u0 + jl * 8);
        float s = 0.f;
#pragma unroll
        for (int xx = 0; xx < 8; ++xx) s += (float)v[xx] * tms[jl * 8 + xx];
        r[i] = s * pv;
      }
      float4 w0 = {r[0], r[1], r[2], r[3]};
      float4 w1 = {r[4], r[5], r[6], r[7]};
      *(float4*)&kls[jl * 68 + cq * 8] = w0;
      *(float4*)&kls[jl * 68 + cq * 8 + 4] = w1;
    }
    int sr = tid >> 3, sd8 = (tid & 7) * 8;
    int jq = tid & 15, nq = tid >> 4;
    float lmA = 0.f, lmB = 0.f;
    float aA1 = 0.f, aA2 = 0.f, aA3 = 0.f, aB1 = 0.f, aB2 = 0.f, aB3 = 0.f;
    int jA = j0 + jq * 2, jB = jA + 1;
    for (int nt = 0; nt < 4; ++nt) {
      int n0 = nc * 128 + nt * 32;
      __syncthreads();
      if (nt == 0) { lmA = lmv[jq * 2]; lmB = lmv[jq * 2 + 1]; }
      {
        size_t gi = (size_t)b * (Nn * Cc) + (size_t)(n0 + sr) * 512 + h * 64 + sd8;
        half8 kv = *(const half8*)(Q + gi);
        float4 k0 = {(float)kv[0], (float)kv[1], (float)kv[2], (float)kv[3]};
        float4 k1 = {(float)kv[4], (float)kv[5], (float)kv[6], (float)kv[7]};
        *(float4*)&Qs[sr * 68 + sd8] = k0;
        *(float4*)&Qs[sr * 68 + sd8 + 4] = k1;
      }
      __syncthreads();
      const float4* q0p = (const float4*)&kls[(jq * 2) * 68];
      const float4* q1p = (const float4*)&kls[(jq * 2 + 1) * 68];
      const float4* k0p = (const float4*)&Qs[(nq * 2) * 68];
      const float4* k1p = (const float4*)&Qs[(nq * 2 + 1) * 68];
      float s00 = 0.f, s01 = 0.f, s10 = 0.f, s11 = 0.f;
#pragma unroll
      for (int i = 0; i < 16; ++i) {
        int dq = (i + tid) & 15;
        float4 q0 = q0p[dq], q1 = q1p[dq];
        float4 k0 = k0p[dq], k1 = k1p[dq];
        s00 += fabsf(q0.x - k0.x) + fabsf(q0.y - k0.y) + fabsf(q0.z - k0.z) + fabsf(q0.w - k0.w);
        s01 += fabsf(q0.x - k1.x) + fabsf(q0.y - k1.y) + fabsf(q0.z - k1.z) + fabsf(q0.w - k1.w);
        s10 += fabsf(q1.x - k0.x) + fabsf(q1.y - k0.y) + fabsf(q1.z - k0.z) + fabsf(q1.w - k0.w);
        s11 += fabsf(q1.x - k1.x) + fabsf(q1.y - k1.y) + fabsf(q1.z - k1.z) + fabsf(q1.w - k1.w);
      }
      int nA = n0 + nq * 2, nB = nA + 1;
      float tA = tm[b * 1024 + nA], tB = tm[b * 1024 + nB];
      float xAa = lapexp(s00) * lmA;
      float xAb = lapexp(s01) * lmA;
      float xBa = lapexp(s10) * lmB;
      float xBb = lapexp(s11) * lmB;
      __half2 pA; pA.x = f2h(xAa); pA.y = f2h(xBa);
      __half2 pB; pB.x = f2h(xAb); pB.y = f2h(xBb);
      *(__half2*)&Pbuf[((size_t)bh * 1024 + nA) * 128 + jA] = pA;
      *(__half2*)&Pbuf[((size_t)bh * 1024 + nB) * 128 + jA] = pB;
      float xt;
      xt = xAa * tA; aA1 += xt; aA2 += xt * xt; aA3 += xt * tA;
      xt = xAb * tB; aA1 += xt; aA2 += xt * xt; aA3 += xt * tB;
      xt = xBa * tA; aB1 += xt; aB2 += xt * xt; aB3 += xt * tA;
      xt = xBb * tB; aB1 += xt; aB2 += xt * xt; aB3 += xt * tB;
    }
    int jl = jq * 2;
    red[(jl * 8 + nq) * 3 + 0] = aA1;
    red[(jl * 8 + nq) * 3 + 1] = aA2;
    red[(jl * 8 + nq) * 3 + 2] = aA3;
    red[((jl + 1) * 8 + nq) * 3 + 0] = aB1;
    red[((jl + 1) * 8 + nq) * 3 + 1] = aB2;
    red[((jl + 1) * 8 + nq) * 3 + 2] = aB3;
    __syncthreads();
    if (tid < 32) {
      float s1 = 0.f, s2 = 0.f, s3 = 0.f;
#pragma unroll
      for (int q = 0; q < 8; ++q) {
        s1 += red[(tid * 8 + q) * 3 + 0];
        s2 += red[(tid * 8 + q) * 3 + 1];
        s3 += red[(tid * 8 + q) * 3 + 2];
      }
      size_t base = ((size_t)(nc * 16 + bh) * 128 + j0 + tid) * 3;
      PS[base] = s1; PS[base + 1] = s2; PS[base + 2] = s3;
    }
  } else if (id < 1024) {
    // ---------------- ktv body (pools QL rows j0..j0+16) -------------------
    int kid = id - 512;
    int jt = kid & 7, bh = (kid >> 3) & 15, nc = kid >> 7;  // nc in [0,4)
    int b = bh >> 3, h = bh & 7;
    int j0 = jt * 16;
    float* qls = (float*)smem;             // 4352
    float* Ks  = (float*)(smem + 4352);    // 8704
    float* Vs  = (float*)(smem + 13056);   // 8704
    float* P   = (float*)(smem + 21760);   // 2560
    float* tms = (float*)(smem + 24320);   // 512 (128 f32)
    float* pmi = (float*)(smem + 24832);   // 64 (16)
    float* lmv = (float*)(smem + 24896);   // 64 (16)
    int u0 = j0 * 8;
    if (tid < 128) tms[tid] = tm[b * 1024 + u0 + tid];
    __syncthreads();
    if (tid < 16) {
      float pm = 0.f;
#pragma unroll
      for (int i = 0; i < 8; ++i) pm += tms[tid * 8 + i];
      pm *= 0.125f;
      pmi[tid] = 0.125f / fmaxf(pm, 1e-6f);
      lmv[tid] = (pm > 0.f) ? 1.f : 0.f;
    }
    __syncthreads();
    {
      // thread (jl=tid>>4, cq=tid&15) pools 4 channels -> 1 float4 write.
      const __half* Qb = Q + (size_t)b * (Nn * Cc) + (size_t)(h * 64) * 1024;
      int jl_ = tid >> 4, cq = tid & 15;
      float pv = pmi[jl_];
      float r[4];
#pragma unroll
      for (int i = 0; i < 4; ++i) {
        int c = cq * 4 + i;
        half8 v = *(const half8*)(Qb + (size_t)c * 1024 + u0 + jl_ * 8);
        float s = 0.f;
#pragma unroll
        for (int xx = 0; xx < 8; ++xx) s += (float)v[xx] * tms[jl_ * 8 + xx];
        r[i] = s * pv;
      }
      float4 w0 = {r[0], r[1], r[2], r[3]};
      *(float4*)&qls[jl_ * 68 + cq * 4] = w0;
    }
    int sr = tid >> 3, sd8 = (tid & 7) * 8;
    int jq = tid & 15, nq = tid >> 4;   // P compute: 16 j x 16 n-pairs
    int jl = tid >> 4, dq4 = tid & 15;  // PV: 16 j x 16 d-quads
    float acc[4] = {};
    for (int nt = 0; nt < 8; ++nt) {
      int n0 = nc * 256 + nt * 32;
      __syncthreads();
      {
        size_t gi = (size_t)b * (Nn * Cc) + (size_t)(n0 + sr) * 512 + h * 64 + sd8;
        half8 kv = *(const half8*)(K + gi);
        half8 vv = *(const half8*)(V + gi);
        float4 k0 = {(float)kv[0], (float)kv[1], (float)kv[2], (float)kv[3]};
        float4 k1 = {(float)kv[4], (float)kv[5], (float)kv[6], (float)kv[7]};
        float4 v0 = {(float)vv[0], (float)vv[1], (float)vv[2], (float)vv[3]};
        float4 v1 = {(float)vv[4], (float)vv[5], (float)vv[6], (float)vv[7]};
        *(float4*)&Ks[sr * 68 + sd8] = k0;
        *(float4*)&Ks[sr * 68 + sd8 + 4] = k1;
        *(float4*)&Vs[sr * 68 + sd8] = v0;
        *(float4*)&Vs[sr * 68 + sd8 + 4] = v1;
      }
      __syncthreads();
      {
        const float4* qp = (const float4*)&qls[jq * 68];
        const float4* k0p = (const float4*)&Ks[(nq * 2) * 68];
        const float4* k1p = (const float4*)&Ks[(nq * 2 + 1) * 68];
        float s0 = 0.f, s1 = 0.f;
#pragma unroll
        for (int i = 0; i < 16; ++i) {
          int dq = (i + tid) & 15;
          float4 qv = qp[dq];
          float4 k0 = k0p[dq], k1 = k1p[dq];
          s0 += fabsf(qv.x - k0.x) + fabsf(qv.y - k0.y) + fabsf(qv.z - k0.z) + fabsf(qv.w - k0.w);
          s1 += fabsf(qv.x - k1.x) + fabsf(qv.y - k1.y) + fabsf(qv.z - k1.z) + fabsf(qv.w - k1.w);
        }
        P[(nq * 2) * 20 + jq] = lapexp(s0);
        P[(nq * 2 + 1) * 20 + jq] = lapexp(s1);
      }
      __syncthreads();
      {
#pragma unroll 8
        for (int n = 0; n < 32; ++n) {
          float p = P[n * 20 + jl];
          float4 v = *(const float4*)&Vs[n * 68 + dq4 * 4];
          acc[0] += p * v.x; acc[1] += p * v.y; acc[2] += p * v.z; acc[3] += p * v.w;
        }
      }
    }
    {
      float lm = lmv[jl];
      float* dst = &KTVp[((size_t)nc * 16 + bh) * 8192 + (size_t)(j0 + jl) * 64 + dq4 * 4];
      float4 o = {acc[0] * lm, acc[1] * lm, acc[2] * lm, acc[3] * lm};
      *(float4*)dst = o;
    }
  } else {
    // ---------------- wbuild body (pools all 128 KL + 16 QL rows) ----------
    int wid = id - 1024;
    int it = wid >> 4, bh = wid & 15;
    int b = bh >> 3, h = bh & 7;
    int i0 = it * 16;
    _Float16* kls16 = (_Float16*)smem;           // 18432 (128x72)
    float* qs  = (float*)(smem + 18432);         // 4352 (16x68)
    float* pm2 = (float*)(smem + 22784);         // 1024 (128x2)
    float* tms = (float*)(smem + 23808);         // 4096 (1024)
    _Float16* ps16 = (_Float16*)(smem + 23808);  // 4224 (16x132) overlaps tms
    for (int e = tid; e < 1024; e += 256) tms[e] = tm[b * 1024 + e];
    __syncthreads();
    if (tid < 128) {
      float pm = 0.f;
#pragma unroll
      for (int i = 0; i < 8; ++i) pm += tms[tid * 8 + i];
      pm *= 0.125f;
      pm2[tid * 2] = 0.125f / fmaxf(pm, 1e-6f);
      pm2[tid * 2 + 1] = (pm > 0.f) ? 1.f : 0.f;
    }
    __syncthreads();
    {
      const __half* Kb = K + (size_t)b * (Nn * Cc) + (size_t)(h * 64) * 1024;
      const __half* Qb = Q + (size_t)b * (Nn * Cc) + (size_t)(h * 64) * 1024;
      // KL: 4 iters; thread (j=g>>3, cq=g&7) pools 8 channels -> half8 write.
#pragma unroll
      for (int k = 0; k < 4; ++k) {
        int g = k * 256 + tid;
        int j = g >> 3, cq = g & 7;
        float pv = pm2[j * 2];
        _Float16 r[8];
#pragma unroll
        for (int i = 0; i < 8; ++i) {
          int c = cq * 8 + i;
          half8 v = *(const half8*)(Kb + (size_t)c * 1024 + j * 8);
          float s = 0.f;
#pragma unroll
          for (int xx = 0; xx < 8; ++xx) s += (float)v[xx] * tms[j * 8 + xx];
          r[i] = (_Float16)(s * pv);
        }
        half8 w0 = {r[0], r[1], r[2], r[3], r[4], r[5], r[6], r[7]};
        *(half8*)&kls16[j * 72 + cq * 8] = w0;
      }
      // QL rows i0..i0+15: thread (il=tid>>4, cq=tid&15) pools 4 ch -> float4.
      {
        int il = tid >> 4, cq = tid & 15;
        float pv = pm2[(i0 + il) * 2];
        float r[4];
#pragma unroll
        for (int i = 0; i < 4; ++i) {
          int c = cq * 4 + i;
          half8 v = *(const half8*)(Qb + (size_t)c * 1024 + (i0 + il) * 8);
          float s = 0.f;
#pragma unroll
          for (int xx = 0; xx < 8; ++xx) s += (float)v[xx] * tms[(i0 + il) * 8 + xx];
          r[i] = s * pv;
        }
        float4 w0 = {r[0], r[1], r[2], r[3]};
        *(float4*)&qs[il * 68 + cq * 4] = w0;
      }
    }
    __syncthreads();
    int jg = tid & 63, ng = tid >> 6;
    int j = jg * 2;
    const _Float16* kArow = &kls16[j * 72];
    const _Float16* kBrow = &kls16[(j + 1) * 72];
    float sA[4] = {}, sB[4] = {};
#pragma unroll
    for (int i = 0; i < 16; ++i) {
      int dq = (i + jg) & 15;
      half4v k4a = *(const half4v*)&kArow[dq * 4];
      half4v k4b = *(const half4v*)&kBrow[dq * 4];
      float4 ka = {(float)k4a[0], (float)k4a[1], (float)k4a[2], (float)k4a[3]};
      float4 kb = {(float)k4b[0], (float)k4b[1], (float)k4b[2], (float)k4b[3]};
#pragma unroll
      for (int r = 0; r < 4; ++r) {
        float4 qv = *(const float4*)&qs[(ng * 4 + r) * 68 + dq * 4];
        sA[r] += fabsf(qv.x - ka.x) + fabsf(qv.y - ka.y) + fabsf(qv.z - ka.z) + fabsf(qv.w - ka.w);
        sB[r] += fabsf(qv.x - kb.x) + fabsf(qv.y - kb.y) + fabsf(qv.z - kb.z) + fabsf(qv.w - kb.w);
      }
    }
    float lmA = pm2[j * 2 + 1], lmB = pm2[(j + 1) * 2 + 1];
#pragma unroll
    for (int r = 0; r < 4; ++r) {
      int i = i0 + ng * 4 + r;
      float lmi = pm2[i * 2 + 1];
      float prA = lmi * lmA, prB = lmi * lmB;
      float dA = (i == j) ? 1.f : 0.f;
      float dB = (i == j + 1) ? 1.f : 0.f;
      ps16[(ng * 4 + r) * 132 + j] =
          (_Float16)(lapexp(sA[r]) * prA + dA * (1.f - prA) + dA * NS_EPS);
      ps16[(ng * 4 + r) * 132 + j + 1] =
          (_Float16)(lapexp(sB[r]) * prB + dB * (1.f - prB) + dB * NS_EPS);
    }
    __syncthreads();
    for (int e = tid; e < 2048; e += 256) {
      _Float16 v = ps16[(e >> 7) * 132 + (e & 127)];
      Wh[(size_t)bh * (Mm * Mm) + (size_t)(i0 + (e >> 7)) * 128 + (e & 127)] =
          *(__half*)&v;
    }
  }
}

// ---------------------------------------------------------------------------
// M2 v2: 1024-thread blocks. Blocks 0..15: ns_solve (16 waves, 32x32 tiles)
// + fused ctx. Block 16: stats_final.
__global__ __launch_bounds__(1024) void fused_phase2(
    const __half* __restrict__ Wh, const float* __restrict__ KTVp,
    const float* __restrict__ PS, const float* __restrict__ tm,
    __half* __restrict__ CTX, float* __restrict__ MU, float* __restrict__ RS) {
  __shared__ __align__(16) char smem[143360];
  int tid = threadIdx.x;
  if (blockIdx.x < 16) {
    // ---------------- ns_solve + ctx body ----------------
    int bh = blockIdx.x;
    _Float16* Ws = (_Float16*)smem;              // 34816
    _Float16* Xa = (_Float16*)(smem + 34816);    // 34816
    _Float16* Xb = (_Float16*)(smem + 69632);    // 34816
    _Float16* Tt = (_Float16*)(smem + 104448);   // 34816
    float* red = (float*)(smem + 139264);        // 4096
    const __half* Wb = Wh + (size_t)bh * 16384;
    float fro = 0.f;
    for (int e = tid; e < 16384; e += 1024) {
      float wv = h2f(Wb[e]);
      Ws[(e >> 7) * 136 + (e & 127)] = (_Float16)wv;
      fro += wv * wv;
    }
    red[tid] = fro;
    __syncthreads();
    for (int off = 512; off > 0; off >>= 1) {
      if (tid < off) red[tid] += red[tid + off];
      __syncthreads();
    }
    float scale = 2.f / (sqrtf(red[0]) + 1e-8f);
    for (int e = tid; e < 16384; e += 1024) {
      int i = e >> 7, k = e & 127;
      Xa[i * 136 + k] = (_Float16)(scale * (float)Ws[k * 136 + i]);
      Xb[i * 136 + k] = (_Float16)(scale * (float)Ws[i * 136 + k]);
    }
    __syncthreads();
    int lane = tid & 63, wv_ = tid >> 6;            // 16 waves
    int wm = (wv_ >> 2) * 32, wn = (wv_ & 3) * 32;  // 4x4 wave grid
    int l15 = lane & 15, quad = lane >> 4;
    for (int it = 0; it < 5; ++it) {
      {
        float4v acc[2][2] = {};
#pragma unroll
        for (int kt = 0; kt < 4; ++kt) {
          half8 a[2], b[2];
#pragma unroll
          for (int mt = 0; mt < 2; ++mt)
            a[mt] = *(const half8*)&Ws[(wm + mt * 16 + l15) * 136 + kt * 32 + quad * 8];
#pragma unroll
          for (int nt = 0; nt < 2; ++nt)
            b[nt] = *(const half8*)&Xb[(wn + nt * 16 + l15) * 136 + kt * 32 + quad * 8];
#pragma unroll
          for (int mt = 0; mt < 2; ++mt)
#pragma unroll
            for (int nt = 0; nt < 2; ++nt)
              acc[mt][nt] =
                  __builtin_amdgcn_mfma_f32_16x16x32_f16(a[mt], b[nt], acc[mt][nt], 0, 0, 0);
        }
#pragma unroll
        for (int mt = 0; mt < 2; ++mt)
#pragma unroll
          for (int r = 0; r < 4; ++r) {
            int i = wm + mt * 16 + quad * 4 + r;
#pragma unroll
            for (int nt = 0; nt < 2; ++nt) {
              int j = wn + nt * 16 + l15;
              Tt[j * 136 + i] = (_Float16)(((i == j) ? 2.f : 0.f) - acc[mt][nt][r]);
            }
          }
      }
      __syncthreads();
      {
        float4v acc[2][2] = {};
#pragma unroll
        for (int kt = 0; kt < 4; ++kt) {
          half8 a[2], b[2];
#pragma unroll
          for (int mt = 0; mt < 2; ++mt)
            a[mt] = *(const half8*)&Xa[(wm + mt * 16 + l15) * 136 + kt * 32 + quad * 8];
#pragma unroll
          for (int nt = 0; nt < 2; ++nt)
            b[nt] = *(const half8*)&Tt[(wn + nt * 16 + l15) * 136 + kt * 32 + quad * 8];
#pragma unroll
          for (int mt = 0; mt < 2; ++mt)
#pragma unroll
            for (int nt = 0; nt < 2; ++nt)
              acc[mt][nt] =
                  __builtin_amdgcn_mfma_f32_16x16x32_f16(a[mt], b[nt], acc[mt][nt], 0, 0, 0);
        }
        __syncthreads();
#pragma unroll
        for (int mt = 0; mt < 2; ++mt)
#pragma unroll
          for (int r = 0; r < 4; ++r) {
            int i = wm + mt * 16 + quad * 4 + r;
#pragma unroll
            for (int nt = 0; nt < 2; ++nt) {
              int j = wn + nt * 16 + l15;
              _Float16 v = (_Float16)acc[mt][nt][r];
              Xa[i * 136 + j] = v;
              Xb[j * 136 + i] = v;
            }
          }
      }
      __syncthreads();
    }
    // ---- fused ctx: KTV = sum_nc KTVp; CTX = X @ KTV.
    float* KTVs = (float*)smem;  // reuse Ws region
    for (int e = tid; e < 8192; e += 1024) {
      float s = KTVp[(size_t)bh * 8192 + e];
#pragma unroll
      for (int nc = 1; nc < 4; ++nc) s += KTVp[((size_t)nc * 16 + bh) * 8192 + e];
      KTVs[(e >> 6) * 68 + (e & 63)] = s;
    }
    __syncthreads();
    int i = tid >> 3, d0 = (tid & 7) * 8;
    float a0 = 0.f, a1 = 0.f, a2 = 0.f, a3 = 0.f;
    float a4 = 0.f, a5 = 0.f, a6 = 0.f, a7 = 0.f;
#pragma unroll 4
    for (int j = 0; j < 128; ++j) {
      float xv = (float)Xa[i * 136 + j];
      float4 k0 = *(const float4*)&KTVs[j * 68 + d0];
      float4 k1 = *(const float4*)&KTVs[j * 68 + d0 + 4];
      a0 += xv * k0.x; a1 += xv * k0.y; a2 += xv * k0.z; a3 += xv * k0.w;
      a4 += xv * k1.x; a5 += xv * k1.y; a6 += xv * k1.z; a7 += xv * k1.w;
    }
    half8 hout = {(_Float16)a0, (_Float16)a1, (_Float16)a2, (_Float16)a3,
                  (_Float16)a4, (_Float16)a5, (_Float16)a6, (_Float16)a7};
    *(half8*)(CTX + (size_t)bh * 8192 + (size_t)i * 64 + d0) = hout;
  } else {
    // ---------------- stats_final body (1024 threads) ----------------
    float (*red2)[2] = (float(*)[2])smem;       // 8192
    float* ts = (float*)(smem + 8192);          // 8
    float a = 0.f, c = 0.f;
    for (int i = tid; i < 2048; i += 1024) { float t = tm[i]; a += t; c += t * t; }
    red2[tid][0] = a; red2[tid][1] = c;
    __syncthreads();
    for (int off = 512; off > 0; off >>= 1) {
      if (tid < off) { red2[tid][0] += red2[tid + off][0]; red2[tid][1] += red2[tid + off][1]; }
      __syncthreads();
    }
    if (tid == 0) { ts[0] = red2[0][0]; ts[1] = red2[0][1]; }
    __syncthreads();
    int hj = tid;
    int h = hj >> 7, j = hj & 127;
    float s1 = 0.f, s2 = 0.f, s3 = 0.f;
#pragma unroll
    for (int nc = 0; nc < 8; ++nc)
#pragma unroll
      for (int b = 0; b < 2; ++b) {
        const float* p = PS + ((size_t)(nc * 16 + b * 8 + h) * 128 + j) * 3;
        s1 += p[0]; s2 += p[1]; s3 += p[2];
      }
    float valid = fmaxf(ts[0], 1.f);
    float mu = s1 / valid;
    float var = (s2 - 2.f * mu * s3 + mu * mu * ts[1]) / valid;
    var = fmaxf(var, 0.f);
    MU[hj] = mu;
    RS[hj] = rsqrtf(var + WHITE_EPS);
  }
}

// ---------------------------------------------------------------------------
// K12: ga v6 — 32-row n-tiles (grid 512 = 2 blocks/CU); direct conv loads.
__global__ __launch_bounds__(256) void ga_fused(
    const __half* __restrict__ Pbuf, const float* __restrict__ MU,
    const float* __restrict__ RS, const __half* __restrict__ CTXg,
    const __half* __restrict__ V, const float* __restrict__ dwc_w,
    const float* __restrict__ dwc_b, const float* __restrict__ tm,
    __half* __restrict__ VL) {
  int bh = blockIdx.y;
  int b = bh >> 3, h = bh & 7;
  int n0 = blockIdx.x * 32;
  __shared__ __half Ps[32][130];
  __shared__ __align__(16) __half2 ctx2[128][32];
  __shared__ float musr[128][2];
  int tid = threadIdx.x;
  for (int e = tid; e < 4096; e += 256)
    Ps[e >> 7][e & 127] = Pbuf[((size_t)bh * 1024 + n0 + (e >> 7)) * 128 + (e & 127)];
  {
    const __half2* cg = (const __half2*)(CTXg + (size_t)bh * 8192);
    for (int e = tid; e < 4096; e += 256) ctx2[e >> 5][e & 31] = cg[e];
  }
  if (tid < 128) { musr[tid][0] = MU[h * 128 + tid]; musr[tid][1] = RS[h * 128 + tid]; }
  __syncthreads();
  int nn = tid >> 4, dq = tid & 15;
  float acc[2][4] = {};
#pragma unroll 2
  for (int j = 0; j < 128; ++j) {
    float mu = musr[j][0], rs = musr[j][1];
    uint2 cc = *(const uint2*)&ctx2[j][dq * 2];
    __half2 c01 = __builtin_bit_cast(__half2, cc.x);
    __half2 c23 = __builtin_bit_cast(__half2, cc.y);
    float c0 = h2f(c01.x), c1 = h2f(c01.y), c2 = h2f(c23.x), c3 = h2f(c23.y);
#pragma unroll
    for (int rr = 0; rr < 2; ++rr) {
      float pj = (h2f(Ps[nn + rr * 16][j]) - mu) * rs;
      acc[rr][0] += pj * c0; acc[rr][1] += pj * c1;
      acc[rr][2] += pj * c2; acc[rr][3] += pj * c3;
    }
  }
#pragma unroll
  for (int rr = 0; rr < 2; ++rr) {
    int t = n0 + nn + rr * 16;
    float tmv = tm[b * 1024 + t];
    float t2 = tmv * tmv;
    float o[4] = {acc[rr][0] * t2, acc[rr][1] * t2, acc[rr][2] * t2, acc[rr][3] * t2};
#pragma unroll
    for (int q = 0; q < 4; ++q) {
      int c = h * 64 + dq * 4 + q;
      float vacc = dwc_b[c];
#pragma unroll
      for (int k = 0; k < 3; ++k) {
        int u = t - 1 + k;
        if (u >= 0 && u < 1024) {
          int n = 2 * c + (u >> 9), ch = u & 511;
          vacc += dwc_w[c * 3 + k] * h2f(V[(size_t)b * (Nn * Cc) + (size_t)n * 512 + ch]);
        }
      }
      o[q] += vacc * tmv;
    }
    size_t base = (size_t)b * (Nn * Cc) + (size_t)t * 512 + h * 64 + dq * 4;
    VL[base] = f2h(o[0]);
    VL[base + 1] = f2h(o[1]);
    VL[base + 2] = f2h(o[2]);
    VL[base + 3] = f2h(o[3]);
  }
}

// ---------------------------------------------------------------------------
// K13: proj via MFMA f16. M=2048, N=512, K=512. 64x64 tiles -> 256 blocks.
__global__ __launch_bounds__(256) void proj_gemm(
    const __half* __restrict__ Ain, const float* __restrict__ w,
    const float* __restrict__ bias, const float* __restrict__ tm,
    float* __restrict__ out) {
  __shared__ _Float16 As[64 * 40];
  __shared__ _Float16 Bs[64 * 40];
  int m0 = blockIdx.x * 64, n0 = blockIdx.y * 64;
  int tid = threadIdx.x;
  int lane = tid & 63, wv = tid >> 6;
  int wm = (wv >> 1) * 32, wn = (wv & 1) * 32;
  int l15 = lane & 15, quad = lane >> 4;
  int srow = tid >> 2, scol = (tid & 3) * 8;
  float4v acc[2][2] = {};
  for (int k0 = 0; k0 < 512; k0 += 32) {
    __syncthreads();
    {
      half8 ha = *(const half8*)(Ain + (size_t)(m0 + srow) * 512 + k0 + scol);
      const float4* gb = (const float4*)(w + (size_t)(n0 + srow) * 512 + k0 + scol);
      float4 b0 = gb[0], b1 = gb[1];
      half8 hb = {(_Float16)b0.x, (_Float16)b0.y, (_Float16)b0.z, (_Float16)b0.w,
                  (_Float16)b1.x, (_Float16)b1.y, (_Float16)b1.z, (_Float16)b1.w};
      int lo = srow * 40 + scol;
      *(half8*)&As[lo] = ha;
      *(half8*)&Bs[lo] = hb;
    }
    __syncthreads();
    half8 a[2], b[2];
#pragma unroll
    for (int mt = 0; mt < 2; ++mt)
      a[mt] = *(const half8*)&As[(wm + mt * 16 + l15) * 40 + quad * 8];
#pragma unroll
    for (int nt = 0; nt < 2; ++nt)
      b[nt] = *(const half8*)&Bs[(wn + nt * 16 + l15) * 40 + quad * 8];
#pragma unroll
    for (int mt = 0; mt < 2; ++mt)
#pragma unroll
      for (int nt = 0; nt < 2; ++nt)
        acc[mt][nt] =
            __builtin_amdgcn_mfma_f32_16x16x32_f16(a[mt], b[nt], acc[mt][nt], 0, 0, 0);
  }
#pragma unroll
  for (int mt = 0; mt < 2; ++mt) {
#pragma unroll
    for (int r = 0; r < 4; ++r) {
      int row = m0 + wm + mt * 16 + quad * 4 + r;
      int b_ = row >> 10, n_ = row & 1023;
      float t = tm[b_ * 1024 + n_];
#pragma unroll
      for (int nt = 0; nt < 2; ++nt) {
        int co = n0 + wn + nt * 16 + l15;
        out[(size_t)row * 512 + co] = (acc[mt][nt][r] + bias[co]) * t;
      }
    }
  }
}

// ---------------------------------------------------------------------------
// Launches: qkv, M1{stats||ktv||wbuild, inline pooling}, M2{ns+ctx ||
// stats_final}, ga, proj  (5).
extern "C" void kernel_launch(void* const* d_in, const int* in_sizes, int n_in,
                              void* d_out, int out_size, void* d_ws, size_t ws_size,
                              hipStream_t stream) {
  const float* x      = (const float*)d_in[0];
  const float* tm     = (const float*)d_in[1];
  const float* qkv_w  = (const float*)d_in[2];
  const float* qkv_b  = (const float*)d_in[3];
  const float* proj_w = (const float*)d_in[4];
  const float* proj_b = (const float*)d_in[5];
  const float* dwc_w  = (const float*)d_in[6];
  const float* dwc_b  = (const float*)d_in[7];
  float* out = (float*)d_out;

  char* wsb = (char*)d_ws;
  __half* Qh  = (__half*)(wsb + 0);
  __half* Kh  = (__half*)(wsb + 2097152);
  __half* Vh  = (__half*)(wsb + 4194304);
  __half* VLh = (__half*)(wsb + 6291456);
  float*  KTVp = (float*)(wsb + 6291456);     // aliases VLh (dead until ga)
  float*  MU  = (float*)(wsb + 8913920);
  float*  RS  = (float*)(wsb + 8918016);
  __half* CTX = (__half*)(wsb + 8922112);
  float*  PS  = (float*)(wsb + 9184256);
  __half* Wh  = (__half*)(wsb + 9380864);

  __half* Pbuf = (__half*)d_out;

  qkv_gemm<<<dim3(16, 12), 256, 0, stream>>>(x, qkv_w, qkv_b, tm, Qh, Kh, Vh);
  fused_phase1<<<1152, 256, 0, stream>>>(Qh, Kh, Vh, tm, Wh, KTVp, PS, Pbuf);
  fused_phase2<<<17, 1024, 0, stream>>>(Wh, KTVp, PS, tm, CTX, MU, RS);
  ga_fused<<<dim3(32, 16), 256, 0, stream>>>(Pbuf, MU, RS, CTX, Vh, dwc_w, dwc_b, tm, VLh);
  proj_gemm<<<dim3(32, 8), 256, 0, stream>>>(VLh, proj_w, proj_b, tm, out);
}

// Round 12
// 196.283 us; speedup vs baseline: 1.0278x; 1.0022x over previous
//
#include <hip/hip_runtime.h>
#include <hip/hip_bf16.h>
#include <hip/hip_fp16.h>

// B=2, N=1024, C=512, H=8, D=64, m=128, p=8
#define Hh 8
#define Bz 2
#define Nn 1024
#define Cc 512
#define Dd 64
#define Mm 128
#define NS_EPS 1e-4f
#define WHITE_EPS 1e-5f
// exp(-s/LAM) = exp2(-s * log2(e)/LAM), LAM=4
#define NEG_L2E_OVER_LAM (-0.3606737602222409f)

__device__ __forceinline__ float h2f(__half v) { return __half2float(v); }
__device__ __forceinline__ __half f2h(float v) { return __float2half(v); }
__device__ __forceinline__ float lapexp(float s) {
  return __builtin_amdgcn_exp2f(s * NEG_L2E_OVER_LAM);
}

typedef _Float16 half8 __attribute__((ext_vector_type(8)));
typedef _Float16 half4v __attribute__((ext_vector_type(4)));
typedef float float4v __attribute__((ext_vector_type(4)));

// ---------------------------------------------------------------------------
// K1: QKV GEMM via MFMA f16. M=2048, N=1536, K=512. Block tile 128x128.
__global__ __launch_bounds__(256) void qkv_gemm(
    const float* __restrict__ x, const float* __restrict__ w,
    const float* __restrict__ bias, const float* __restrict__ tm,
    __half* __restrict__ Q, __half* __restrict__ K, __half* __restrict__ V) {
  __shared__ _Float16 As[128 * 40];
  __shared__ _Float16 Bs[128 * 40];
  int m0 = blockIdx.x * 128, n0 = blockIdx.y * 128;
  int tid = threadIdx.x;
  int lane = tid & 63, wv = tid >> 6;
  int wm = (wv >> 1) * 64, wn = (wv & 1) * 64;
  int l15 = lane & 15, quad = lane >> 4;
  int srow = tid >> 1, shalf = tid & 1;
  float4v acc[4][4] = {};
  for (int k0 = 0; k0 < 512; k0 += 32) {
    __syncthreads();
    {
      const float4* ga = (const float4*)(x + (size_t)(m0 + srow) * 512 + k0 + shalf * 16);
      const float4* gb = (const float4*)(w + (size_t)(n0 + srow) * 512 + k0 + shalf * 16);
      float4 a0 = ga[0], a1 = ga[1], a2 = ga[2], a3 = ga[3];
      float4 b0 = gb[0], b1 = gb[1], b2 = gb[2], b3 = gb[3];
      half8 ha0 = {(_Float16)a0.x, (_Float16)a0.y, (_Float16)a0.z, (_Float16)a0.w,
                   (_Float16)a1.x, (_Float16)a1.y, (_Float16)a1.z, (_Float16)a1.w};
      half8 ha1 = {(_Float16)a2.x, (_Float16)a2.y, (_Float16)a2.z, (_Float16)a2.w,
                   (_Float16)a3.x, (_Float16)a3.y, (_Float16)a3.z, (_Float16)a3.w};
      half8 hb0 = {(_Float16)b0.x, (_Float16)b0.y, (_Float16)b0.z, (_Float16)b0.w,
                   (_Float16)b1.x, (_Float16)b1.y, (_Float16)b1.z, (_Float16)b1.w};
      half8 hb1 = {(_Float16)b2.x, (_Float16)b2.y, (_Float16)b2.z, (_Float16)b2.w,
                   (_Float16)b3.x, (_Float16)b3.y, (_Float16)b3.z, (_Float16)b3.w};
      int lo = srow * 40 + shalf * 16;
      *(half8*)&As[lo] = ha0;
      *(half8*)&As[lo + 8] = ha1;
      *(half8*)&Bs[lo] = hb0;
      *(half8*)&Bs[lo + 8] = hb1;
    }
    __syncthreads();
    half8 a[4], b[4];
#pragma unroll
    for (int mt = 0; mt < 4; ++mt)
      a[mt] = *(const half8*)&As[(wm + mt * 16 + l15) * 40 + quad * 8];
#pragma unroll
    for (int nt = 0; nt < 4; ++nt)
      b[nt] = *(const half8*)&Bs[(wn + nt * 16 + l15) * 40 + quad * 8];
#pragma unroll
    for (int mt = 0; mt < 4; ++mt)
#pragma unroll
      for (int nt = 0; nt < 4; ++nt)
        acc[mt][nt] =
            __builtin_amdgcn_mfma_f32_16x16x32_f16(a[mt], b[nt], acc[mt][nt], 0, 0, 0);
  }
#pragma unroll
  for (int mt = 0; mt < 4; ++mt) {
#pragma unroll
    for (int r = 0; r < 4; ++r) {
      int row = m0 + wm + mt * 16 + quad * 4 + r;
      int b_ = row >> 10, n_ = row & 1023;
      float t = tm[b_ * 1024 + n_];
#pragma unroll
      for (int nt = 0; nt < 4; ++nt) {
        int c3 = n0 + wn + nt * 16 + l15;
        float v = (acc[mt][nt][r] + bias[c3]) * t;
        int sec = c3 >> 9, ch = c3 & 511;
        __half* dst = (sec == 0) ? Q : (sec == 1 ? K : V);
        dst[(size_t)b_ * (Nn * Cc) + (size_t)n_ * 512 + ch] = f2h(v);
      }
    }
  }
}

// ---------------------------------------------------------------------------
// M1 v7: phase-1 (r8 base) + T14 async-STAGE split: next-tile global loads
// prefetched into regs BEFORE compute of current tile (stats & ktv nt-loops).
// stats (0..511) || ktv (512..1023) || wbuild (1024..1151).
__global__ __launch_bounds__(256) void fused_phase1(
    const __half* __restrict__ Q, const __half* __restrict__ K,
    const __half* __restrict__ V, const float* __restrict__ tm,
    __half* __restrict__ Wh, float* __restrict__ KTVp,
    float* __restrict__ PS, __half* __restrict__ Pbuf) {
  __shared__ __align__(16) char smem[31232];
  int id = blockIdx.x;
  int tid = threadIdx.x;
  if (id < 512) {
    // ---------------- stats_partial body (pools KL rows j0..j0+32) --------
    int jt = id & 3, bh = (id >> 2) & 15, nc = id >> 6;  // nc in [0,8)
    int b = bh >> 3, h = bh & 7;
    int j0 = jt * 32;
    float* kls = (float*)smem;             // 8704
    float* Qs  = (float*)(smem + 8704);    // 8704
    float* red = (float*)(smem + 17408);   // 3072
    float* tms = (float*)(smem + 20480);   // 1024 (256 f32)
    float* pmi = (float*)(smem + 21504);   // 128 (32)
    float* lmv = (float*)(smem + 21632);   // 128 (32)
    int u0 = j0 * 8;
    int sr = tid >> 3, sd8 = (tid & 7) * 8;
    size_t giB = (size_t)b * (Nn * Cc) + (size_t)sr * 512 + h * 64 + sd8;
    // T14: prefetch tile 0 — latency hidden under tm staging + pooling.
    half8 pf = *(const half8*)(Q + giB + (size_t)(nc * 128) * 512);
    tms[tid] = tm[b * 1024 + u0 + tid];
    __syncthreads();
    if (tid < 32) {
      float pm = 0.f;
#pragma unroll
      for (int i = 0; i < 8; ++i) pm += tms[tid * 8 + i];
      pm *= 0.125f;
      pmi[tid] = 0.125f / fmaxf(pm, 1e-6f);
      lmv[tid] = (pm > 0.f) ? 1.f : 0.f;
    }
    __syncthreads();
    {
      // thread (jl=tid>>3, cq=tid&7) pools 8 channels -> 2 float4 writes.
      const __half* Kb = K + (size_t)b * (Nn * Cc) + (size_t)(h * 64) * 1024;
      int jl = tid >> 3, cq = tid & 7;
      float pv = pmi[jl];
      float r[8];
#pragma unroll
      for (int i = 0; i < 8; ++i) {
        int c = cq * 8 + i;
        half8 v = *(const half8*)(Kb + (size_t)c * 1024 + u0 + jl * 8);
        float s = 0.f;
#pragma unroll
        for (int xx = 0; xx < 8; ++xx) s += (float)v[xx] * tms[jl * 8 + xx];
        r[i] = s * pv;
      }
      float4 w0 = {r[0], r[1], r[2], r[3]};
      float4 w1 = {r[4], r[5], r[6], r[7]};
      *(float4*)&kls[jl * 68 + cq * 8] = w0;
      *(float4*)&kls[jl * 68 + cq * 8 + 4] = w1;
    }
    int jq = tid & 15, nq = tid >> 4;
    float lmA = 0.f, lmB = 0.f;
    float aA1 = 0.f, aA2 = 0.f, aA3 = 0.f, aB1 = 0.f, aB2 = 0.f, aB3 = 0.f;
    int jA = j0 + jq * 2, jB = jA + 1;
    for (int nt = 0; nt < 4; ++nt) {
      int n0 = nc * 128 + nt * 32;
      __syncthreads();
      if (nt == 0) { lmA = lmv[jq * 2]; lmB = lmv[jq * 2 + 1]; }
      {
        float4 k0 = {(float)pf[0], (float)pf[1], (float)pf[2], (float)pf[3]};
        float4 k1 = {(float)pf[4], (float)pf[5], (float)pf[6], (float)pf[7]};
        *(float4*)&Qs[sr * 68 + sd8] = k0;
        *(float4*)&Qs[sr * 68 + sd8 + 4] = k1;
      }
      if (nt < 3) pf = *(const half8*)(Q + giB + (size_t)(n0 + 32) * 512);
      __syncthreads();
      const float4* q0p = (const float4*)&kls[(jq * 2) * 68];
      const float4* q1p = (const float4*)&kls[(jq * 2 + 1) * 68];
      const float4* k0p = (const float4*)&Qs[(nq * 2) * 68];
      const float4* k1p = (const float4*)&Qs[(nq * 2 + 1) * 68];
      float s00 = 0.f, s01 = 0.f, s10 = 0.f, s11 = 0.f;
#pragma unroll
      for (int i = 0; i < 16; ++i) {
        int dq = (i + tid) & 15;
        float4 q0 = q0p[dq], q1 = q1p[dq];
        float4 k0 = k0p[dq], k1 = k1p[dq];
        s00 += fabsf(q0.x - k0.x) + fabsf(q0.y - k0.y) + fabsf(q0.z - k0.z) + fabsf(q0.w - k0.w);
        s01 += fabsf(q0.x - k1.x) + fabsf(q0.y - k1.y) + fabsf(q0.z - k1.z) + fabsf(q0.w - k1.w);
        s10 += fabsf(q1.x - k0.x) + fabsf(q1.y - k0.y) + fabsf(q1.z - k0.z) + fabsf(q1.w - k0.w);
        s11 += fabsf(q1.x - k1.x) + fabsf(q1.y - k1.y) + fabsf(q1.z - k1.z) + fabsf(q1.w - k1.w);
      }
      int nA = n0 + nq * 2, nB = nA + 1;
      float tA = tm[b * 1024 + nA], tB = tm[b * 1024 + nB];
      float xAa = lapexp(s00) * lmA;
      float xAb = lapexp(s01) * lmA;
      float xBa = lapexp(s10) * lmB;
      float xBb = lapexp(s11) * lmB;
      __half2 pA; pA.x = f2h(xAa); pA.y = f2h(xBa);
      __half2 pB; pB.x = f2h(xAb); pB.y = f2h(xBb);
      *(__half2*)&Pbuf[((size_t)bh * 1024 + nA) * 128 + jA] = pA;
      *(__half2*)&Pbuf[((size_t)bh * 1024 + nB) * 128 + jA] = pB;
      float xt;
      xt = xAa * tA; aA1 += xt; aA2 += xt * xt; aA3 += xt * tA;
      xt = xAb * tB; aA1 += xt; aA2 += xt * xt; aA3 += xt * tB;
      xt = xBa * tA; aB1 += xt; aB2 += xt * xt; aB3 += xt * tA;
      xt = xBb * tB; aB1 += xt; aB2 += xt * xt; aB3 += xt * tB;
    }
    int jl = jq * 2;
    red[(jl * 8 + nq) * 3 + 0] = aA1;
    red[(jl * 8 + nq) * 3 + 1] = aA2;
    red[(jl * 8 + nq) * 3 + 2] = aA3;
    red[((jl + 1) * 8 + nq) * 3 + 0] = aB1;
    red[((jl + 1) * 8 + nq) * 3 + 1] = aB2;
    red[((jl + 1) * 8 + nq) * 3 + 2] = aB3;
    __syncthreads();
    if (tid < 32) {
      float s1 = 0.f, s2 = 0.f, s3 = 0.f;
#pragma unroll
      for (int q = 0; q < 8; ++q) {
        s1 += red[(tid * 8 + q) * 3 + 0];
        s2 += red[(tid * 8 + q) * 3 + 1];
        s3 += red[(tid * 8 + q) * 3 + 2];
      }
      size_t base = ((size_t)(nc * 16 + bh) * 128 + j0 + tid) * 3;
      PS[base] = s1; PS[base + 1] = s2; PS[base + 2] = s3;
    }
  } else if (id < 1024) {
    // ---------------- ktv body (pools QL rows j0..j0+16) -------------------
    int kid = id - 512;
    int jt = kid & 7, bh = (kid >> 3) & 15, nc = kid >> 7;  // nc in [0,4)
    int b = bh >> 3, h = bh & 7;
    int j0 = jt * 16;
    float* qls = (float*)smem;             // 4352
    float* Ks  = (float*)(smem + 4352);    // 8704
    float* Vs  = (float*)(smem + 13056);   // 8704
    float* P   = (float*)(smem + 21760);   // 2560
    float* tms = (float*)(smem + 24320);   // 512 (128 f32)
    float* pmi = (float*)(smem + 24832);   // 64 (16)
    float* lmv = (float*)(smem + 24896);   // 64 (16)
    int u0 = j0 * 8;
    int sr = tid >> 3, sd8 = (tid & 7) * 8;
    size_t giB = (size_t)b * (Nn * Cc) + (size_t)sr * 512 + h * 64 + sd8;
    // T14: prefetch tile 0 of K and V.
    half8 pfk = *(const half8*)(K + giB + (size_t)(nc * 256) * 512);
    half8 pfv = *(const half8*)(V + giB + (size_t)(nc * 256) * 512);
    if (tid < 128) tms[tid] = tm[b * 1024 + u0 + tid];
    __syncthreads();
    if (tid < 16) {
      float pm = 0.f;
#pragma unroll
      for (int i = 0; i < 8; ++i) pm += tms[tid * 8 + i];
      pm *= 0.125f;
      pmi[tid] = 0.125f / fmaxf(pm, 1e-6f);
      lmv[tid] = (pm > 0.f) ? 1.f : 0.f;
    }
    __syncthreads();
    {
      // thread (jl=tid>>4, cq=tid&15) pools 4 channels -> 1 float4 write.
      const __half* Qb = Q + (size_t)b * (Nn * Cc) + (size_t)(h * 64) * 1024;
      int jl_ = tid >> 4, cq = tid & 15;
      float pv = pmi[jl_];
      float r[4];
#pragma unroll
      for (int i = 0; i < 4; ++i) {
        int c = cq * 4 + i;
        half8 v = *(const half8*)(Qb + (size_t)c * 1024 + u0 + jl_ * 8);
        float s = 0.f;
#pragma unroll
        for (int xx = 0; xx < 8; ++xx) s += (float)v[xx] * tms[jl_ * 8 + xx];
        r[i] = s * pv;
      }
      float4 w0 = {r[0], r[1], r[2], r[3]};
      *(float4*)&qls[jl_ * 68 + cq * 4] = w0;
    }
    int jq = tid & 15, nq = tid >> 4;   // P compute: 16 j x 16 n-pairs
    int jl = tid >> 4, dq4 = tid & 15;  // PV: 16 j x 16 d-quads
    float acc[4] = {};
    for (int nt = 0; nt < 8; ++nt) {
      int n0 = nc * 256 + nt * 32;
      __syncthreads();
      {
        float4 k0 = {(float)pfk[0], (float)pfk[1], (float)pfk[2], (float)pfk[3]};
        float4 k1 = {(float)pfk[4], (float)pfk[5], (float)pfk[6], (float)pfk[7]};
        float4 v0 = {(float)pfv[0], (float)pfv[1], (float)pfv[2], (float)pfv[3]};
        float4 v1 = {(float)pfv[4], (float)pfv[5], (float)pfv[6], (float)pfv[7]};
        *(float4*)&Ks[sr * 68 + sd8] = k0;
        *(float4*)&Ks[sr * 68 + sd8 + 4] = k1;
        *(float4*)&Vs[sr * 68 + sd8] = v0;
        *(float4*)&Vs[sr * 68 + sd8 + 4] = v1;
      }
      if (nt < 7) {
        pfk = *(const half8*)(K + giB + (size_t)(n0 + 32) * 512);
        pfv = *(const half8*)(V + giB + (size_t)(n0 + 32) * 512);
      }
      __syncthreads();
      {
        const float4* qp = (const float4*)&qls[jq * 68];
        const float4* k0p = (const float4*)&Ks[(nq * 2) * 68];
        const float4* k1p = (const float4*)&Ks[(nq * 2 + 1) * 68];
        float s0 = 0.f, s1 = 0.f;
#pragma unroll
        for (int i = 0; i < 16; ++i) {
          int dq = (i + tid) & 15;
          float4 qv = qp[dq];
          float4 k0 = k0p[dq], k1 = k1p[dq];
          s0 += fabsf(qv.x - k0.x) + fabsf(qv.y - k0.y) + fabsf(qv.z - k0.z) + fabsf(qv.w - k0.w);
          s1 += fabsf(qv.x - k1.x) + fabsf(qv.y - k1.y) + fabsf(qv.z - k1.z) + fabsf(qv.w - k1.w);
        }
        P[(nq * 2) * 20 + jq] = lapexp(s0);
        P[(nq * 2 + 1) * 20 + jq] = lapexp(s1);
      }
      __syncthreads();
      {
#pragma unroll 8
        for (int n = 0; n < 32; ++n) {
          float p = P[n * 20 + jl];
          float4 v = *(const float4*)&Vs[n * 68 + dq4 * 4];
          acc[0] += p * v.x; acc[1] += p * v.y; acc[2] += p * v.z; acc[3] += p * v.w;
        }
      }
    }
    {
      float lm = lmv[jl];
      float* dst = &KTVp[((size_t)nc * 16 + bh) * 8192 + (size_t)(j0 + jl) * 64 + dq4 * 4];
      float4 o = {acc[0] * lm, acc[1] * lm, acc[2] * lm, acc[3] * lm};
      *(float4*)dst = o;
    }
  } else {
    // ---------------- wbuild body (pools all 128 KL + 16 QL rows) ----------
    int wid = id - 1024;
    int it = wid >> 4, bh = wid & 15;
    int b = bh >> 3, h = bh & 7;
    int i0 = it * 16;
    _Float16* kls16 = (_Float16*)smem;           // 18432 (128x72)
    float* qs  = (float*)(smem + 18432);         // 4352 (16x68)
    float* pm2 = (float*)(smem + 22784);         // 1024 (128x2)
    float* tms = (float*)(smem + 23808);         // 4096 (1024)
    _Float16* ps16 = (_Float16*)(smem + 23808);  // 4224 (16x132) overlaps tms
    for (int e = tid; e < 1024; e += 256) tms[e] = tm[b * 1024 + e];
    __syncthreads();
    if (tid < 128) {
      float pm = 0.f;
#pragma unroll
      for (int i = 0; i < 8; ++i) pm += tms[tid * 8 + i];
      pm *= 0.125f;
      pm2[tid * 2] = 0.125f / fmaxf(pm, 1e-6f);
      pm2[tid * 2 + 1] = (pm > 0.f) ? 1.f : 0.f;
    }
    __syncthreads();
    {
      const __half* Kb = K + (size_t)b * (Nn * Cc) + (size_t)(h * 64) * 1024;
      const __half* Qb = Q + (size_t)b * (Nn * Cc) + (size_t)(h * 64) * 1024;
      // KL: 4 iters; thread (j=g>>3, cq=g&7) pools 8 channels -> half8 write.
#pragma unroll
      for (int k = 0; k < 4; ++k) {
        int g = k * 256 + tid;
        int j = g >> 3, cq = g & 7;
        float pv = pm2[j * 2];
        _Float16 r[8];
#pragma unroll
        for (int i = 0; i < 8; ++i) {
          int c = cq * 8 + i;
          half8 v = *(const half8*)(Kb + (size_t)c * 1024 + j * 8);
          float s = 0.f;
#pragma unroll
          for (int xx = 0; xx < 8; ++xx) s += (float)v[xx] * tms[j * 8 + xx];
          r[i] = (_Float16)(s * pv);
        }
        half8 w0 = {r[0], r[1], r[2], r[3], r[4], r[5], r[6], r[7]};
        *(half8*)&kls16[j * 72 + cq * 8] = w0;
      }
      // QL rows i0..i0+15: thread (il=tid>>4, cq=tid&15) pools 4 ch -> float4.
      {
        int il = tid >> 4, cq = tid & 15;
        float pv = pm2[(i0 + il) * 2];
        float r[4];
#pragma unroll
        for (int i = 0; i < 4; ++i) {
          int c = cq * 4 + i;
          half8 v = *(const half8*)(Qb + (size_t)c * 1024 + (i0 + il) * 8);
          float s = 0.f;
#pragma unroll
          for (int xx = 0; xx < 8; ++xx) s += (float)v[xx] * tms[(i0 + il) * 8 + xx];
          r[i] = s * pv;
        }
        float4 w0 = {r[0], r[1], r[2], r[3]};
        *(float4*)&qs[il * 68 + cq * 4] = w0;
      }
    }
    __syncthreads();
    int jg = tid & 63, ng = tid >> 6;
    int j = jg * 2;
    const _Float16* kArow = &kls16[j * 72];
    const _Float16* kBrow = &kls16[(j + 1) * 72];
    float sA[4] = {}, sB[4] = {};
#pragma unroll
    for (int i = 0; i < 16; ++i) {
      int dq = (i + jg) & 15;
      half4v k4a = *(const half4v*)&kArow[dq * 4];
      half4v k4b = *(const half4v*)&kBrow[dq * 4];
      float4 ka = {(float)k4a[0], (float)k4a[1], (float)k4a[2], (float)k4a[3]};
      float4 kb = {(float)k4b[0], (float)k4b[1], (float)k4b[2], (float)k4b[3]};
#pragma unroll
      for (int r = 0; r < 4; ++r) {
        float4 qv = *(const float4*)&qs[(ng * 4 + r) * 68 + dq * 4];
        sA[r] += fabsf(qv.x - ka.x) + fabsf(qv.y - ka.y) + fabsf(qv.z - ka.z) + fabsf(qv.w - ka.w);
        sB[r] += fabsf(qv.x - kb.x) + fabsf(qv.y - kb.y) + fabsf(qv.z - kb.z) + fabsf(qv.w - kb.w);
      }
    }
    float lmA = pm2[j * 2 + 1], lmB = pm2[(j + 1) * 2 + 1];
#pragma unroll
    for (int r = 0; r < 4; ++r) {
      int i = i0 + ng * 4 + r;
      float lmi = pm2[i * 2 + 1];
      float prA = lmi * lmA, prB = lmi * lmB;
      float dA = (i == j) ? 1.f : 0.f;
      float dB = (i == j + 1) ? 1.f : 0.f;
      ps16[(ng * 4 + r) * 132 + j] =
          (_Float16)(lapexp(sA[r]) * prA + dA * (1.f - prA) + dA * NS_EPS);
      ps16[(ng * 4 + r) * 132 + j + 1] =
          (_Float16)(lapexp(sB[r]) * prB + dB * (1.f - prB) + dB * NS_EPS);
    }
    __syncthreads();
    for (int e = tid; e < 2048; e += 256) {
      _Float16 v = ps16[(e >> 7) * 132 + (e & 127)];
      Wh[(size_t)bh * (Mm * Mm) + (size_t)(i0 + (e >> 7)) * 128 + (e & 127)] =
          *(__half*)&v;
    }
  }
}

// ---------------------------------------------------------------------------
// M2 v2: 1024-thread blocks. Blocks 0..15: ns_solve (16 waves, 32x32 tiles)
// + fused ctx. Block 16: stats_final.
__global__ __launch_bounds__(1024) void fused_phase2(
    const __half* __restrict__ Wh, const float* __restrict__ KTVp,
    const float* __restrict__ PS, const float* __restrict__ tm,
    __half* __restrict__ CTX, float* __restrict__ MU, float* __restrict__ RS) {
  __shared__ __align__(16) char smem[143360];
  int tid = threadIdx.x;
  if (blockIdx.x < 16) {
    // ---------------- ns_solve + ctx body ----------------
    int bh = blockIdx.x;
    _Float16* Ws = (_Float16*)smem;              // 34816
    _Float16* Xa = (_Float16*)(smem + 34816);    // 34816
    _Float16* Xb = (_Float16*)(smem + 69632);    // 34816
    _Float16* Tt = (_Float16*)(smem + 104448);   // 34816
    float* red = (float*)(smem + 139264);        // 4096
    const __half* Wb = Wh + (size_t)bh * 16384;
    float fro = 0.f;
    for (int e = tid; e < 16384; e += 1024) {
      float wv = h2f(Wb[e]);
      Ws[(e >> 7) * 136 + (e & 127)] = (_Float16)wv;
      fro += wv * wv;
    }
    red[tid] = fro;
    __syncthreads();
    for (int off = 512; off > 0; off >>= 1) {
      if (tid < off) red[tid] += red[tid + off];
      __syncthreads();
    }
    float scale = 2.f / (sqrtf(red[0]) + 1e-8f);
    for (int e = tid; e < 16384; e += 1024) {
      int i = e >> 7, k = e & 127;
      Xa[i * 136 + k] = (_Float16)(scale * (float)Ws[k * 136 + i]);
      Xb[i * 136 + k] = (_Float16)(scale * (float)Ws[i * 136 + k]);
    }
    __syncthreads();
    int lane = tid & 63, wv_ = tid >> 6;            // 16 waves
    int wm = (wv_ >> 2) * 32, wn = (wv_ & 3) * 32;  // 4x4 wave grid
    int l15 = lane & 15, quad = lane >> 4;
    for (int it = 0; it < 5; ++it) {
      {
        float4v acc[2][2] = {};
#pragma unroll
        for (int kt = 0; kt < 4; ++kt) {
          half8 a[2], b[2];
#pragma unroll
          for (int mt = 0; mt < 2; ++mt)
            a[mt] = *(const half8*)&Ws[(wm + mt * 16 + l15) * 136 + kt * 32 + quad * 8];
#pragma unroll
          for (int nt = 0; nt < 2; ++nt)
            b[nt] = *(const half8*)&Xb[(wn + nt * 16 + l15) * 136 + kt * 32 + quad * 8];
#pragma unroll
          for (int mt = 0; mt < 2; ++mt)
#pragma unroll
            for (int nt = 0; nt < 2; ++nt)
              acc[mt][nt] =
                  __builtin_amdgcn_mfma_f32_16x16x32_f16(a[mt], b[nt], acc[mt][nt], 0, 0, 0);
        }
#pragma unroll
        for (int mt = 0; mt < 2; ++mt)
#pragma unroll
          for (int r = 0; r < 4; ++r) {
            int i = wm + mt * 16 + quad * 4 + r;
#pragma unroll
            for (int nt = 0; nt < 2; ++nt) {
              int j = wn + nt * 16 + l15;
              Tt[j * 136 + i] = (_Float16)(((i == j) ? 2.f : 0.f) - acc[mt][nt][r]);
            }
          }
      }
      __syncthreads();
      {
        float4v acc[2][2] = {};
#pragma unroll
        for (int kt = 0; kt < 4; ++kt) {
          half8 a[2], b[2];
#pragma unroll
          for (int mt = 0; mt < 2; ++mt)
            a[mt] = *(const half8*)&Xa[(wm + mt * 16 + l15) * 136 + kt * 32 + quad * 8];
#pragma unroll
          for (int nt = 0; nt < 2; ++nt)
            b[nt] = *(const half8*)&Tt[(wn + nt * 16 + l15) * 136 + kt * 32 + quad * 8];
#pragma unroll
          for (int mt = 0; mt < 2; ++mt)
#pragma unroll
            for (int nt = 0; nt < 2; ++nt)
              acc[mt][nt] =
                  __builtin_amdgcn_mfma_f32_16x16x32_f16(a[mt], b[nt], acc[mt][nt], 0, 0, 0);
        }
        __syncthreads();
#pragma unroll
        for (int mt = 0; mt < 2; ++mt)
#pragma unroll
          for (int r = 0; r < 4; ++r) {
            int i = wm + mt * 16 + quad * 4 + r;
#pragma unroll
            for (int nt = 0; nt < 2; ++nt) {
              int j = wn + nt * 16 + l15;
              _Float16 v = (_Float16)acc[mt][nt][r];
              Xa[i * 136 + j] = v;
              Xb[j * 136 + i] = v;
            }
          }
      }
      __syncthreads();
    }
    // ---- fused ctx: KTV = sum_nc KTVp; CTX = X @ KTV.
    float* KTVs = (float*)smem;  // reuse Ws region
    for (int e = tid; e < 8192; e += 1024) {
      float s = KTVp[(size_t)bh * 8192 + e];
#pragma unroll
      for (int nc = 1; nc < 4; ++nc) s += KTVp[((size_t)nc * 16 + bh) * 8192 + e];
      KTVs[(e >> 6) * 68 + (e & 63)] = s;
    }
    __syncthreads();
    int i = tid >> 3, d0 = (tid & 7) * 8;
    float a0 = 0.f, a1 = 0.f, a2 = 0.f, a3 = 0.f;
    float a4 = 0.f, a5 = 0.f, a6 = 0.f, a7 = 0.f;
#pragma unroll 4
    for (int j = 0; j < 128; ++j) {
      float xv = (float)Xa[i * 136 + j];
      float4 k0 = *(const float4*)&KTVs[j * 68 + d0];
      float4 k1 = *(const float4*)&KTVs[j * 68 + d0 + 4];
      a0 += xv * k0.x; a1 += xv * k0.y; a2 += xv * k0.z; a3 += xv * k0.w;
      a4 += xv * k1.x; a5 += xv * k1.y; a6 += xv * k1.z; a7 += xv * k1.w;
    }
    half8 hout = {(_Float16)a0, (_Float16)a1, (_Float16)a2, (_Float16)a3,
                  (_Float16)a4, (_Float16)a5, (_Float16)a6, (_Float16)a7};
    *(half8*)(CTX + (size_t)bh * 8192 + (size_t)i * 64 + d0) = hout;
  } else {
    // ---------------- stats_final body (1024 threads) ----------------
    float (*red2)[2] = (float(*)[2])smem;       // 8192
    float* ts = (float*)(smem + 8192);          // 8
    float a = 0.f, c = 0.f;
    for (int i = tid; i < 2048; i += 1024) { float t = tm[i]; a += t; c += t * t; }
    red2[tid][0] = a; red2[tid][1] = c;
    __syncthreads();
    for (int off = 512; off > 0; off >>= 1) {
      if (tid < off) { red2[tid][0] += red2[tid + off][0]; red2[tid][1] += red2[tid + off][1]; }
      __syncthreads();
    }
    if (tid == 0) { ts[0] = red2[0][0]; ts[1] = red2[0][1]; }
    __syncthreads();
    int hj = tid;
    int h = hj >> 7, j = hj & 127;
    float s1 = 0.f, s2 = 0.f, s3 = 0.f;
#pragma unroll
    for (int nc = 0; nc < 8; ++nc)
#pragma unroll
      for (int b = 0; b < 2; ++b) {
        const float* p = PS + ((size_t)(nc * 16 + b * 8 + h) * 128 + j) * 3;
        s1 += p[0]; s2 += p[1]; s3 += p[2];
      }
    float valid = fmaxf(ts[0], 1.f);
    float mu = s1 / valid;
    float var = (s2 - 2.f * mu * s3 + mu * mu * ts[1]) / valid;
    var = fmaxf(var, 0.f);
    MU[hj] = mu;
    RS[hj] = rsqrtf(var + WHITE_EPS);
  }
}

// ---------------------------------------------------------------------------
// K12: ga v6 — 32-row n-tiles (grid 512 = 2 blocks/CU); direct conv loads.
__global__ __launch_bounds__(256) void ga_fused(
    const __half* __restrict__ Pbuf, const float* __restrict__ MU,
    const float* __restrict__ RS, const __half* __restrict__ CTXg,
    const __half* __restrict__ V, const float* __restrict__ dwc_w,
    const float* __restrict__ dwc_b, const float* __restrict__ tm,
    __half* __restrict__ VL) {
  int bh = blockIdx.y;
  int b = bh >> 3, h = bh & 7;
  int n0 = blockIdx.x * 32;
  __shared__ __half Ps[32][130];
  __shared__ __align__(16) __half2 ctx2[128][32];
  __shared__ float musr[128][2];
  int tid = threadIdx.x;
  for (int e = tid; e < 4096; e += 256)
    Ps[e >> 7][e & 127] = Pbuf[((size_t)bh * 1024 + n0 + (e >> 7)) * 128 + (e & 127)];
  {
    const __half2* cg = (const __half2*)(CTXg + (size_t)bh * 8192);
    for (int e = tid; e < 4096; e += 256) ctx2[e >> 5][e & 31] = cg[e];
  }
  if (tid < 128) { musr[tid][0] = MU[h * 128 + tid]; musr[tid][1] = RS[h * 128 + tid]; }
  __syncthreads();
  int nn = tid >> 4, dq = tid & 15;
  float acc[2][4] = {};
#pragma unroll 2
  for (int j = 0; j < 128; ++j) {
    float mu = musr[j][0], rs = musr[j][1];
    uint2 cc = *(const uint2*)&ctx2[j][dq * 2];
    __half2 c01 = __builtin_bit_cast(__half2, cc.x);
    __half2 c23 = __builtin_bit_cast(__half2, cc.y);
    float c0 = h2f(c01.x), c1 = h2f(c01.y), c2 = h2f(c23.x), c3 = h2f(c23.y);
#pragma unroll
    for (int rr = 0; rr < 2; ++rr) {
      float pj = (h2f(Ps[nn + rr * 16][j]) - mu) * rs;
      acc[rr][0] += pj * c0; acc[rr][1] += pj * c1;
      acc[rr][2] += pj * c2; acc[rr][3] += pj * c3;
    }
  }
#pragma unroll
  for (int rr = 0; rr < 2; ++rr) {
    int t = n0 + nn + rr * 16;
    float tmv = tm[b * 1024 + t];
    float t2 = tmv * tmv;
    float o[4] = {acc[rr][0] * t2, acc[rr][1] * t2, acc[rr][2] * t2, acc[rr][3] * t2};
#pragma unroll
    for (int q = 0; q < 4; ++q) {
      int c = h * 64 + dq * 4 + q;
      float vacc = dwc_b[c];
#pragma unroll
      for (int k = 0; k < 3; ++k) {
        int u = t - 1 + k;
        if (u >= 0 && u < 1024) {
          int n = 2 * c + (u >> 9), ch = u & 511;
          vacc += dwc_w[c * 3 + k] * h2f(V[(size_t)b * (Nn * Cc) + (size_t)n * 512 + ch]);
        }
      }
      o[q] += vacc * tmv;
    }
    size_t base = (size_t)b * (Nn * Cc) + (size_t)t * 512 + h * 64 + dq * 4;
    VL[base] = f2h(o[0]);
    VL[base + 1] = f2h(o[1]);
    VL[base + 2] = f2h(o[2]);
    VL[base + 3] = f2h(o[3]);
  }
}

// ---------------------------------------------------------------------------
// K13: proj via MFMA f16. M=2048, N=512, K=512. 64x64 tiles -> 256 blocks.
__global__ __launch_bounds__(256) void proj_gemm(
    const __half* __restrict__ Ain, const float* __restrict__ w,
    const float* __restrict__ bias, const float* __restrict__ tm,
    float* __restrict__ out) {
  __shared__ _Float16 As[64 * 40];
  __shared__ _Float16 Bs[64 * 40];
  int m0 = blockIdx.x * 64, n0 = blockIdx.y * 64;
  int tid = threadIdx.x;
  int lane = tid & 63, wv = tid >> 6;
  int wm = (wv >> 1) * 32, wn = (wv & 1) * 32;
  int l15 = lane & 15, quad = lane >> 4;
  int srow = tid >> 2, scol = (tid & 3) * 8;
  float4v acc[2][2] = {};
  for (int k0 = 0; k0 < 512; k0 += 32) {
    __syncthreads();
    {
      half8 ha = *(const half8*)(Ain + (size_t)(m0 + srow) * 512 + k0 + scol);
      const float4* gb = (const float4*)(w + (size_t)(n0 + srow) * 512 + k0 + scol);
      float4 b0 = gb[0], b1 = gb[1];
      half8 hb = {(_Float16)b0.x, (_Float16)b0.y, (_Float16)b0.z, (_Float16)b0.w,
                  (_Float16)b1.x, (_Float16)b1.y, (_Float16)b1.z, (_Float16)b1.w};
      int lo = srow * 40 + scol;
      *(half8*)&As[lo] = ha;
      *(half8*)&Bs[lo] = hb;
    }
    __syncthreads();
    half8 a[2], b[2];
#pragma unroll
    for (int mt = 0; mt < 2; ++mt)
      a[mt] = *(const half8*)&As[(wm + mt * 16 + l15) * 40 + quad * 8];
#pragma unroll
    for (int nt = 0; nt < 2; ++nt)
      b[nt] = *(const half8*)&Bs[(wn + nt * 16 + l15) * 40 + quad * 8];
#pragma unroll
    for (int mt = 0; mt < 2; ++mt)
#pragma unroll
      for (int nt = 0; nt < 2; ++nt)
        acc[mt][nt] =
            __builtin_amdgcn_mfma_f32_16x16x32_f16(a[mt], b[nt], acc[mt][nt], 0, 0, 0);
  }
#pragma unroll
  for (int mt = 0; mt < 2; ++mt) {
#pragma unroll
    for (int r = 0; r < 4; ++r) {
      int row = m0 + wm + mt * 16 + quad * 4 + r;
      int b_ = row >> 10, n_ = row & 1023;
      float t = tm[b_ * 1024 + n_];
#pragma unroll
      for (int nt = 0; nt < 2; ++nt) {
        int co = n0 + wn + nt * 16 + l15;
        out[(size_t)row * 512 + co] = (acc[mt][nt][r] + bias[co]) * t;
      }
    }
  }
}

// ---------------------------------------------------------------------------
// Launches: qkv, M1{stats||ktv||wbuild, inline pooling, T14 prefetch},
// M2{ns+ctx || stats_final}, ga, proj  (5).
extern "C" void kernel_launch(void* const* d_in, const int* in_sizes, int n_in,
                              void* d_out, int out_size, void* d_ws, size_t ws_size,
                              hipStream_t stream) {
  const float* x      = (const float*)d_in[0];
  const float* tm     = (const float*)d_in[1];
  const float* qkv_w  = (const float*)d_in[2];
  const float* qkv_b  = (const float*)d_in[3];
  const float* proj_w = (const float*)d_in[4];
  const float* proj_b = (const float*)d_in[5];
  const float* dwc_w  = (const float*)d_in[6];
  const float* dwc_b  = (const float*)d_in[7];
  float* out = (float*)d_out;

  char* wsb = (char*)d_ws;
  __half* Qh  = (__half*)(wsb + 0);
  __half* Kh  = (__half*)(wsb + 2097152);
  __half* Vh  = (__half*)(wsb + 4194304);
  __half* VLh = (__half*)(wsb + 6291456);
  float*  KTVp = (float*)(wsb + 6291456);     // aliases VLh (dead until ga)
  float*  MU  = (float*)(wsb + 8913920);
  float*  RS  = (float*)(wsb + 8918016);
  __half* CTX = (__half*)(wsb + 8922112);
  float*  PS  = (float*)(wsb + 9184256);
  __half* Wh  = (__half*)(wsb + 9380864);

  __half* Pbuf = (__half*)d_out;

  qkv_gemm<<<dim3(16, 12), 256, 0, stream>>>(x, qkv_w, qkv_b, tm, Qh, Kh, Vh);
  fused_phase1<<<1152, 256, 0, stream>>>(Qh, Kh, Vh, tm, Wh, KTVp, PS, Pbuf);
  fused_phase2<<<17, 1024, 0, stream>>>(Wh, KTVp, PS, tm, CTX, MU, RS);
  ga_fused<<<dim3(32, 16), 256, 0, stream>>>(Pbuf, MU, RS, CTX, Vh, dwc_w, dwc_b, tm, VLh);
  proj_gemm<<<dim3(32, 8), 256, 0, stream>>>(VLh, proj_w, proj_b, tm, out);
}